// Round 1
// baseline (1137.357 us; speedup 1.0000x reference)
//
#include <hip/hip_runtime.h>
#include <math.h>
#include <stddef.h>

#define NN 8192
#define NHEAD 3
#define NEG_SLOPE 0.2f

__device__ __forceinline__ float lrelu(float x) { return x > 0.f ? x : NEG_SLOPE * x; }
__device__ __forceinline__ float sigf(float x) { return 1.f / (1.f + __expf(-x)); }

// ---------------- CSR build ----------------
__global__ void k_zero(int* __restrict__ p, int n) {
    int i = blockIdx.x * blockDim.x + threadIdx.x;
    if (i < n) p[i] = 0;
}

__global__ void k_count(const int* __restrict__ dst, int* __restrict__ cnt, int E) {
    int i = blockIdx.x * blockDim.x + threadIdx.x;
    if (i < E) atomicAdd(&cnt[dst[i]], 1);
}

__global__ void k_dinv(const int* __restrict__ cnt, float* __restrict__ dinv) {
    int i = blockIdx.x * blockDim.x + threadIdx.x;
    if (i < NN) dinv[i] = rsqrtf((float)(cnt[i] + 1));   // +1 self-loop
}

// exclusive scan of cnt[0..NN) into row_ptr[0..NN]
__global__ void k_scan(const int* __restrict__ cnt, int* __restrict__ row_ptr) {
    __shared__ int part[1024];
    int t = threadIdx.x;
    int base = t * 8;
    int loc[8];
    int s = 0;
    #pragma unroll
    for (int j = 0; j < 8; ++j) { loc[j] = s; s += cnt[base + j]; }
    part[t] = s;
    __syncthreads();
    for (int off = 1; off < 1024; off <<= 1) {
        int v = (t >= off) ? part[t - off] : 0;
        __syncthreads();
        part[t] += v;
        __syncthreads();
    }
    int pre = (t == 0) ? 0 : part[t - 1];
    #pragma unroll
    for (int j = 0; j < 8; ++j) row_ptr[base + j] = pre + loc[j];
    if (t == 1023) row_ptr[NN] = part[1023];
}

__global__ void k_fill(const int* __restrict__ src, const int* __restrict__ dst,
                       const int* __restrict__ row_ptr, int* __restrict__ cursor,
                       int* __restrict__ csr_src, int E) {
    int i = blockIdx.x * blockDim.x + threadIdx.x;
    if (i < E) {
        int d = dst[i];
        csr_src[row_ptr[d] + atomicAdd(&cursor[d], 1)] = src[i];
    }
}

// ---------------- generic fp32 GEMM: C[M,N] = A[M,K] @ B[K,N] ----------------
// BM=128, BN=64, BK=16, 256 threads, 8x4 per thread. M%128==0, N%64==0, K%16==0.
__global__ __launch_bounds__(256) void k_gemm(const float* __restrict__ A,
                                              const float* __restrict__ B,
                                              float* __restrict__ C,
                                              int M, int K, int N) {
    __shared__ float As[16][128];   // k-major
    __shared__ float Bs[16][64];
    int tid = threadIdx.x;
    int tx = tid & 15, ty = tid >> 4;
    int m0 = blockIdx.x * 128, n0 = blockIdx.y * 64;
    float acc[8][4];
    #pragma unroll
    for (int i = 0; i < 8; ++i)
        #pragma unroll
        for (int j = 0; j < 4; ++j) acc[i][j] = 0.f;

    for (int k0 = 0; k0 < K; k0 += 16) {
        #pragma unroll
        for (int c = 0; c < 2; ++c) {           // A tile, transpose to k-major
            int lin = tid + c * 256;            // 0..511 float4 slots
            int row = lin >> 2, kc = lin & 3;
            float4 v = *(const float4*)(A + (size_t)(m0 + row) * K + k0 + kc * 4);
            As[kc * 4 + 0][row] = v.x; As[kc * 4 + 1][row] = v.y;
            As[kc * 4 + 2][row] = v.z; As[kc * 4 + 3][row] = v.w;
        }
        {                                       // B tile, direct
            int k = tid >> 4, nc = tid & 15;
            *(float4*)&Bs[k][nc * 4] = *(const float4*)(B + (size_t)(k0 + k) * N + n0 + nc * 4);
        }
        __syncthreads();
        #pragma unroll
        for (int k = 0; k < 16; ++k) {
            float a[8], b[4];
            *(float4*)&a[0] = *(float4*)&As[k][ty * 4];
            *(float4*)&a[4] = *(float4*)&As[k][64 + ty * 4];
            *(float4*)&b[0] = *(float4*)&Bs[k][tx * 4];
            #pragma unroll
            for (int i = 0; i < 8; ++i)
                #pragma unroll
                for (int j = 0; j < 4; ++j) acc[i][j] += a[i] * b[j];
        }
        __syncthreads();
    }
    #pragma unroll
    for (int i = 0; i < 8; ++i) {
        int row = m0 + ty * 4 + (i & 3) + (i >> 2) * 64;
        float4 v; v.x = acc[i][0]; v.y = acc[i][1]; v.z = acc[i][2]; v.w = acc[i][3];
        *(float4*)(C + (size_t)row * N + n0 + tx * 4) = v;
    }
}

// ---------------- GCN aggregate: out[d] = dinv[d]*(sum dinv[s] v[s] + dinv[d] v[d]) + b ----
template <int RELU>
__global__ void k_gcn_agg(const float* __restrict__ v, const float* __restrict__ dinv,
                          const int* __restrict__ row_ptr, const int* __restrict__ csr_src,
                          const float* __restrict__ bias, float* __restrict__ out, int D) {
    int d = blockIdx.x;
    int t = threadIdx.x;                         // blockDim == D
    float dd = dinv[d];
    float acc = dd * v[(size_t)d * D + t];
    int e0 = row_ptr[d], e1 = row_ptr[d + 1];
    for (int j = e0; j < e1; ++j) {
        int s = csr_src[j];
        acc += dinv[s] * v[(size_t)s * D + t];
    }
    float o = dd * acc + bias[t];
    if (RELU) o = fmaxf(o, 0.f);
    out[(size_t)d * D + t] = o;
}

// ---------------- GAT: per-node attention logits a_s.h, a_d.h ----------------
__global__ void k_gat_logits(const float* __restrict__ h, const float* __restrict__ a_s,
                             const float* __restrict__ a_d, float* __restrict__ as_n,
                             float* __restrict__ ad_n, int D) {
    int n = blockIdx.x;
    int hd = threadIdx.x >> 6, lane = threadIdx.x & 63;   // block = 192 = 3 waves
    float ss = 0.f, sd = 0.f;
    for (int dm = lane; dm < D; dm += 64) {
        float hv = h[(size_t)n * (NHEAD * D) + hd * D + dm];
        ss += hv * a_s[hd * D + dm];
        sd += hv * a_d[hd * D + dm];
    }
    #pragma unroll
    for (int off = 32; off; off >>= 1) {
        ss += __shfl_down(ss, off);
        sd += __shfl_down(sd, off);
    }
    if (lane == 0) { as_n[n * NHEAD + hd] = ss; ad_n[n * NHEAD + hd] = sd; }
}

// ---------------- GAT: segment softmax weights (max, denom, weights) ----------------
__global__ void k_gat_attn(const float* __restrict__ as_n, const float* __restrict__ ad_n,
                           const int* __restrict__ row_ptr, const int* __restrict__ csr_src,
                           float* __restrict__ w_csr, float* __restrict__ w_self) {
    int d = blockIdx.x;
    int lane = threadIdx.x;                       // block = 64
    int e0 = row_ptr[d], e1 = row_ptr[d + 1];
    for (int hd = 0; hd < NHEAD; ++hd) {
        float add = ad_n[d * NHEAD + hd];
        float eself = lrelu(as_n[d * NHEAD + hd] + add);
        float mx = (lane == 0) ? eself : -INFINITY;
        for (int j = e0 + lane; j < e1; j += 64)
            mx = fmaxf(mx, lrelu(as_n[csr_src[j] * NHEAD + hd] + add));
        #pragma unroll
        for (int off = 32; off; off >>= 1) mx = fmaxf(mx, __shfl_xor(mx, off));
        float sm = (lane == 0) ? __expf(eself - mx) : 0.f;
        for (int j = e0 + lane; j < e1; j += 64)
            sm += __expf(lrelu(as_n[csr_src[j] * NHEAD + hd] + add) - mx);
        #pragma unroll
        for (int off = 32; off; off >>= 1) sm += __shfl_xor(sm, off);
        float inv = 1.f / sm;
        if (lane == 0) w_self[d * NHEAD + hd] = __expf(eself - mx) * inv;
        for (int j = e0 + lane; j < e1; j += 64)
            w_csr[(size_t)j * NHEAD + hd] =
                __expf(lrelu(as_n[csr_src[j] * NHEAD + hd] + add) - mx) * inv;
    }
}

// ---------------- GAT layer1 aggregate (concat) + bias + relu ----------------
__global__ void k_gat_agg1(const float* __restrict__ h, const float* __restrict__ w_csr,
                           const float* __restrict__ w_self, const int* __restrict__ row_ptr,
                           const int* __restrict__ csr_src, const float* __restrict__ bias,
                           float* __restrict__ out) {
    int d = blockIdx.x;
    int t = threadIdx.x;                          // block = 384, col = t
    int hd = t >> 7;                              // t / 128
    float acc = w_self[d * NHEAD + hd] * h[(size_t)d * 384 + t];
    int e0 = row_ptr[d], e1 = row_ptr[d + 1];
    for (int j = e0; j < e1; ++j) {
        int s = csr_src[j];
        acc += w_csr[(size_t)j * NHEAD + hd] * h[(size_t)s * 384 + t];
    }
    out[(size_t)d * 384 + t] = fmaxf(acc + bias[t], 0.f);
}

// ---------------- GAT layer2 aggregate + head-mean + bias ----------------
__global__ void k_gat_agg2(const float* __restrict__ h, const float* __restrict__ w_csr,
                           const float* __restrict__ w_self, const int* __restrict__ row_ptr,
                           const int* __restrict__ csr_src, const float* __restrict__ bias,
                           float* __restrict__ out) {
    int d = blockIdx.x;
    int t = threadIdx.x;                          // block = 64, dim = t
    int e0 = row_ptr[d], e1 = row_ptr[d + 1];
    float tot = 0.f;
    for (int hd = 0; hd < NHEAD; ++hd) {
        float acc = w_self[d * NHEAD + hd] * h[(size_t)d * 192 + hd * 64 + t];
        for (int j = e0; j < e1; ++j) {
            int s = csr_src[j];
            acc += w_csr[(size_t)j * NHEAD + hd] * h[(size_t)s * 192 + hd * 64 + t];
        }
        tot += acc;
    }
    out[(size_t)d * 64 + t] = tot * (1.f / 3.f) + bias[t];
}

// ---------------- branch combine: z = mu + eps*exp(lv), max-accumulate ----------------
template <int FIRST>
__global__ void k_combine(const float* __restrict__ mu, const float* __restrict__ lv,
                          const float* __restrict__ eps, float* __restrict__ mu_o,
                          float* __restrict__ lv_o, float* __restrict__ z_o) {
    int i = blockIdx.x * blockDim.x + threadIdx.x;      // NN*64 total
    float m = mu[i], l = lv[i];
    float z = m + eps[i] * __expf(l);
    if (FIRST) { mu_o[i] = m; lv_o[i] = l; z_o[i] = z; }
    else {
        mu_o[i] = fmaxf(mu_o[i], m);
        lv_o[i] = fmaxf(lv_o[i], l);
        z_o[i]  = fmaxf(z_o[i], z);
    }
}

// ---------------- transpose z[NN][64] -> zt[64][NN] ----------------
__global__ void k_transpose(const float* __restrict__ z, float* __restrict__ zt) {
    __shared__ float tl[64][65];
    int n0 = blockIdx.x * 64;
    int t = threadIdx.x;                          // 256
    #pragma unroll
    for (int c = 0; c < 16; ++c) {
        int idx = t + c * 256;                    // 0..4095
        int n = idx >> 6, k = idx & 63;
        tl[k][n] = z[(size_t)(n0 + n) * 64 + k];
    }
    __syncthreads();
    #pragma unroll
    for (int c = 0; c < 16; ++c) {
        int idx = t + c * 256;
        int k = idx >> 6, n = idx & 63;
        zt[(size_t)k * NN + n0 + n] = tl[k][n];
    }
}

// ---------------- adj = sigmoid(Z Z^T), Z^T provided k-major ----------------
__global__ __launch_bounds__(256) void k_adj(const float* __restrict__ zt,
                                             float* __restrict__ out) {
    __shared__ float Za[64][128];                 // k-major, 32 KB
    __shared__ float Zb[64][128];                 // 32 KB
    int tid = threadIdx.x;
    int tx = tid & 15, ty = tid >> 4;
    int r0 = blockIdx.x * 128, c0 = blockIdx.y * 128;
    #pragma unroll
    for (int c = 0; c < 8; ++c) {
        int lin = tid + c * 256;                  // 0..2047 float4 slots
        int k = lin >> 5, rc = lin & 31;
        *(float4*)&Za[k][rc * 4] = *(const float4*)(zt + (size_t)k * NN + r0 + rc * 4);
        *(float4*)&Zb[k][rc * 4] = *(const float4*)(zt + (size_t)k * NN + c0 + rc * 4);
    }
    __syncthreads();
    float acc[8][8];
    #pragma unroll
    for (int i = 0; i < 8; ++i)
        #pragma unroll
        for (int j = 0; j < 8; ++j) acc[i][j] = 0.f;
    #pragma unroll 4
    for (int k = 0; k < 64; ++k) {
        float a[8], b[8];
        *(float4*)&a[0] = *(float4*)&Za[k][ty * 4];
        *(float4*)&a[4] = *(float4*)&Za[k][64 + ty * 4];
        *(float4*)&b[0] = *(float4*)&Zb[k][tx * 4];
        *(float4*)&b[4] = *(float4*)&Zb[k][64 + tx * 4];
        #pragma unroll
        for (int i = 0; i < 8; ++i)
            #pragma unroll
            for (int j = 0; j < 8; ++j) acc[i][j] += a[i] * b[j];
    }
    #pragma unroll
    for (int i = 0; i < 8; ++i) {
        int row = r0 + ty * 4 + (i & 3) + (i >> 2) * 64;
        float4 v;
        v.x = sigf(acc[i][0]); v.y = sigf(acc[i][1]); v.z = sigf(acc[i][2]); v.w = sigf(acc[i][3]);
        *(float4*)(out + (size_t)row * NN + c0 + tx * 4) = v;
        v.x = sigf(acc[i][4]); v.y = sigf(acc[i][5]); v.z = sigf(acc[i][6]); v.w = sigf(acc[i][7]);
        *(float4*)(out + (size_t)row * NN + c0 + 64 + tx * 4) = v;
    }
}

extern "C" void kernel_launch(void* const* d_in, const int* in_sizes, int n_in,
                              void* d_out, int out_size, void* d_ws, size_t ws_size,
                              hipStream_t stream) {
    const float* x  = (const float*)d_in[0];
    const int*   ei = (const int*)d_in[1];
    const int E = in_sizes[1] / 2;
    const int* src = ei;
    const int* dst = ei + E;

    const float* gcn_W1  = (const float*)d_in[2];
    const float* gcn_b1  = (const float*)d_in[3];
    const float* gcn_Wmu = (const float*)d_in[4];
    const float* gcn_bmu = (const float*)d_in[5];
    const float* gcn_Wlv = (const float*)d_in[6];
    const float* gcn_blv = (const float*)d_in[7];
    const float* gat_W1  = (const float*)d_in[8];
    const float* gat_as1 = (const float*)d_in[9];
    const float* gat_ad1 = (const float*)d_in[10];
    const float* gat_b1  = (const float*)d_in[11];
    const float* gat_Wmu = (const float*)d_in[12];
    const float* gat_asmu= (const float*)d_in[13];
    const float* gat_admu= (const float*)d_in[14];
    const float* gat_bmu = (const float*)d_in[15];
    const float* gat_Wlv = (const float*)d_in[16];
    const float* gat_aslv= (const float*)d_in[17];
    const float* gat_adlv= (const float*)d_in[18];
    const float* gat_blv = (const float*)d_in[19];
    const float* eps_gcn = (const float*)d_in[20];
    const float* eps_gat = (const float*)d_in[21];

    // ---- workspace carve ----
    char* p = (char*)d_ws;
    auto alloc = [&](size_t bytes) {
        void* r = (void*)p;
        p += (bytes + 255) & ~(size_t)255;
        return r;
    };
    int*   cnt     = (int*)alloc((size_t)NN * 4);
    int*   cursor  = (int*)alloc((size_t)NN * 4);        // adjacent to cnt
    int*   row_ptr = (int*)alloc((size_t)(NN + 1) * 4);
    int*   csr_src = (int*)alloc((size_t)E * 4);
    float* dinv    = (float*)alloc((size_t)NN * 4);
    float* as_n    = (float*)alloc((size_t)NN * NHEAD * 4);
    float* ad_n    = (float*)alloc((size_t)NN * NHEAD * 4);
    float* w_self  = (float*)alloc((size_t)NN * NHEAD * 4);
    float* w_csr   = (float*)alloc((size_t)E * NHEAD * 4);
    float* xw1     = (float*)alloc((size_t)NN * 384 * 4);  // also GCN xw [NN,128]
    float* h1      = (float*)alloc((size_t)NN * 384 * 4);  // also GCN h [NN,128]
    float* h2      = (float*)alloc((size_t)NN * 192 * 4);  // also GCN mu/lv pre [NN,64]
    float* mu_t    = (float*)alloc((size_t)NN * 64 * 4);
    float* lv_t    = (float*)alloc((size_t)NN * 64 * 4);
    float* zmax    = (float*)alloc((size_t)NN * 64 * 4);
    float* zt      = (float*)alloc((size_t)NN * 64 * 4);

    float* adj  = (float*)d_out;
    float* mu_o = adj + (size_t)NN * NN;
    float* lv_o = mu_o + (size_t)NN * 64;

    // ---- CSR build ----
    k_zero<<<(2 * NN + 255) / 256, 256, 0, stream>>>(cnt, 2 * NN);  // cnt + cursor
    k_count<<<(E + 255) / 256, 256, 0, stream>>>(dst, cnt, E);
    k_dinv<<<(NN + 255) / 256, 256, 0, stream>>>(cnt, dinv);
    k_scan<<<1, 1024, 0, stream>>>(cnt, row_ptr);
    k_fill<<<(E + 255) / 256, 256, 0, stream>>>(src, dst, row_ptr, cursor, csr_src, E);

    // ---- GCN branches ----
    for (int i = 0; i < 2; ++i) {
        k_gemm<<<dim3(NN / 128, 2), 256, 0, stream>>>(x, gcn_W1 + (size_t)i * 512 * 128, xw1,
                                                      NN, 512, 128);
        k_gcn_agg<1><<<NN, 128, 0, stream>>>(xw1, dinv, row_ptr, csr_src,
                                             gcn_b1 + i * 128, h1, 128);
        k_gemm<<<dim3(NN / 128, 1), 256, 0, stream>>>(h1, gcn_Wmu + (size_t)i * 128 * 64, h2,
                                                      NN, 128, 64);
        k_gcn_agg<0><<<NN, 64, 0, stream>>>(h2, dinv, row_ptr, csr_src,
                                            gcn_bmu + i * 64, mu_t, 64);
        k_gemm<<<dim3(NN / 128, 1), 256, 0, stream>>>(h1, gcn_Wlv + (size_t)i * 128 * 64, h2,
                                                      NN, 128, 64);
        k_gcn_agg<0><<<NN, 64, 0, stream>>>(h2, dinv, row_ptr, csr_src,
                                            gcn_blv + i * 64, lv_t, 64);
        if (i == 0)
            k_combine<1><<<NN * 64 / 256, 256, 0, stream>>>(mu_t, lv_t, eps_gcn + (size_t)i * NN * 64,
                                                            mu_o, lv_o, zmax);
        else
            k_combine<0><<<NN * 64 / 256, 256, 0, stream>>>(mu_t, lv_t, eps_gcn + (size_t)i * NN * 64,
                                                            mu_o, lv_o, zmax);
    }

    // ---- GAT branches ----
    for (int i = 0; i < 2; ++i) {
        k_gemm<<<dim3(NN / 128, 6), 256, 0, stream>>>(x, gat_W1 + (size_t)i * 512 * 384, xw1,
                                                      NN, 512, 384);
        k_gat_logits<<<NN, 192, 0, stream>>>(xw1, gat_as1 + i * 384, gat_ad1 + i * 384,
                                             as_n, ad_n, 128);
        k_gat_attn<<<NN, 64, 0, stream>>>(as_n, ad_n, row_ptr, csr_src, w_csr, w_self);
        k_gat_agg1<<<NN, 384, 0, stream>>>(xw1, w_csr, w_self, row_ptr, csr_src,
                                           gat_b1 + i * 384, h1);
        // mu head
        k_gemm<<<dim3(NN / 128, 3), 256, 0, stream>>>(h1, gat_Wmu + (size_t)i * 384 * 192, h2,
                                                      NN, 384, 192);
        k_gat_logits<<<NN, 192, 0, stream>>>(h2, gat_asmu + i * 192, gat_admu + i * 192,
                                             as_n, ad_n, 64);
        k_gat_attn<<<NN, 64, 0, stream>>>(as_n, ad_n, row_ptr, csr_src, w_csr, w_self);
        k_gat_agg2<<<NN, 64, 0, stream>>>(h2, w_csr, w_self, row_ptr, csr_src,
                                          gat_bmu + i * 64, mu_t);
        // lv head
        k_gemm<<<dim3(NN / 128, 3), 256, 0, stream>>>(h1, gat_Wlv + (size_t)i * 384 * 192, h2,
                                                      NN, 384, 192);
        k_gat_logits<<<NN, 192, 0, stream>>>(h2, gat_aslv + i * 192, gat_adlv + i * 192,
                                             as_n, ad_n, 64);
        k_gat_attn<<<NN, 64, 0, stream>>>(as_n, ad_n, row_ptr, csr_src, w_csr, w_self);
        k_gat_agg2<<<NN, 64, 0, stream>>>(h2, w_csr, w_self, row_ptr, csr_src,
                                          gat_blv + i * 64, lv_t);
        k_combine<0><<<NN * 64 / 256, 256, 0, stream>>>(mu_t, lv_t, eps_gat + (size_t)i * NN * 64,
                                                        mu_o, lv_o, zmax);
    }

    // ---- adjacency ----
    k_transpose<<<NN / 64, 256, 0, stream>>>(zmax, zt);
    k_adj<<<dim3(NN / 128, NN / 128), 256, 0, stream>>>(zt, adj);
}

// Round 2
// 897.356 us; speedup vs baseline: 1.2675x; 1.2675x over previous
//
#include <hip/hip_runtime.h>
#include <hip/hip_bf16.h>
#include <math.h>
#include <stddef.h>

#define NN 8192
#define NHEAD 3
#define NEG_SLOPE 0.2f

typedef __attribute__((ext_vector_type(8))) short short8;
typedef __attribute__((ext_vector_type(4))) float f32x4;

__device__ __forceinline__ float lrelu(float x) { return x > 0.f ? x : NEG_SLOPE * x; }
__device__ __forceinline__ float sigf(float x) { return 1.f / (1.f + __expf(-x)); }

__device__ __forceinline__ void splitbf(float x, unsigned short& hu, unsigned short& lu) {
    __hip_bfloat16 h = __float2bfloat16(x);
    float hf = __bfloat162float(h);
    __hip_bfloat16 l = __float2bfloat16(x - hf);
    hu = *reinterpret_cast<unsigned short*>(&h);
    lu = *reinterpret_cast<unsigned short*>(&l);
}

// ---------------- CSR build ----------------
__global__ void k_zero(int* __restrict__ p, int n) {
    int i = blockIdx.x * blockDim.x + threadIdx.x;
    if (i < n) p[i] = 0;
}

__global__ void k_count(const int* __restrict__ dst, int* __restrict__ cnt, int E) {
    int i = blockIdx.x * blockDim.x + threadIdx.x;
    if (i < E) atomicAdd(&cnt[dst[i]], 1);
}

__global__ void k_dinv(const int* __restrict__ cnt, float* __restrict__ dinv) {
    int i = blockIdx.x * blockDim.x + threadIdx.x;
    if (i < NN) dinv[i] = rsqrtf((float)(cnt[i] + 1));   // +1 self-loop
}

__global__ void k_scan(const int* __restrict__ cnt, int* __restrict__ row_ptr) {
    __shared__ int part[1024];
    int t = threadIdx.x;
    int base = t * 8;
    int loc[8];
    int s = 0;
    #pragma unroll
    for (int j = 0; j < 8; ++j) { loc[j] = s; s += cnt[base + j]; }
    part[t] = s;
    __syncthreads();
    for (int off = 1; off < 1024; off <<= 1) {
        int v = (t >= off) ? part[t - off] : 0;
        __syncthreads();
        part[t] += v;
        __syncthreads();
    }
    int pre = (t == 0) ? 0 : part[t - 1];
    #pragma unroll
    for (int j = 0; j < 8; ++j) row_ptr[base + j] = pre + loc[j];
    if (t == 1023) row_ptr[NN] = part[1023];
}

__global__ void k_fill(const int* __restrict__ src, const int* __restrict__ dst,
                       const int* __restrict__ row_ptr, int* __restrict__ cursor,
                       int* __restrict__ csr_src, int E) {
    int i = blockIdx.x * blockDim.x + threadIdx.x;
    if (i < E) {
        int d = dst[i];
        csr_src[row_ptr[d] + atomicAdd(&cursor[d], 1)] = src[i];
    }
}

// ---------------- split kernels ----------------
// x [NN,512] fp32 -> x2 [NN,1024] bf16 (hi|lo)
__global__ void k_split_x(const float* __restrict__ x, unsigned short* __restrict__ x2) {
    int i = blockIdx.x * 256 + threadIdx.x;     // over NN*512/4
    int m = i >> 7, k4 = (i & 127) * 4;
    float4 v = *(const float4*)(x + (size_t)m * 512 + k4);
    unsigned short h[4], l[4];
    splitbf(v.x, h[0], l[0]); splitbf(v.y, h[1], l[1]);
    splitbf(v.z, h[2], l[2]); splitbf(v.w, h[3], l[3]);
    ushort4 hv; hv.x = h[0]; hv.y = h[1]; hv.z = h[2]; hv.w = h[3];
    ushort4 lv; lv.x = l[0]; lv.y = l[1]; lv.z = l[2]; lv.w = l[3];
    *(ushort4*)&x2[(size_t)m * 1024 + k4] = hv;
    *(ushort4*)&x2[(size_t)m * 1024 + 512 + k4] = lv;
}

// zmax [NN,64] fp32 -> z2 [NN,128] bf16 (hi|lo)
__global__ void k_split_z(const float* __restrict__ z, unsigned short* __restrict__ z2) {
    int i = blockIdx.x * 256 + threadIdx.x;     // over NN*64/4
    int m = i >> 4, k4 = (i & 15) * 4;
    float4 v = *(const float4*)(z + (size_t)m * 64 + k4);
    unsigned short h[4], l[4];
    splitbf(v.x, h[0], l[0]); splitbf(v.y, h[1], l[1]);
    splitbf(v.z, h[2], l[2]); splitbf(v.w, h[3], l[3]);
    ushort4 hv; hv.x = h[0]; hv.y = h[1]; hv.z = h[2]; hv.w = h[3];
    ushort4 lv; lv.x = l[0]; lv.y = l[1]; lv.z = l[2]; lv.w = l[3];
    *(ushort4*)&z2[(size_t)m * 128 + k4] = hv;
    *(ushort4*)&z2[(size_t)m * 128 + 64 + k4] = lv;
}

// W [K,N] fp32 -> Wt [N,2K] bf16 (hi|lo), batched over blockIdx.z branches
__global__ void k_wsplitT(const float* __restrict__ W, unsigned short* __restrict__ Wt,
                          int K, int N) {
    int b = blockIdx.z;
    W += (size_t)b * K * N;
    Wt += (size_t)b * N * 2 * K;
    int k0 = blockIdx.x * 32, n0 = blockIdx.y * 32;
    __shared__ float tl[32][33];
    int tid = threadIdx.x;
    int r = tid >> 5, cc = tid & 31;
    #pragma unroll
    for (int c = 0; c < 4; ++c)
        tl[r + c * 8][cc] = W[(size_t)(k0 + r + c * 8) * N + n0 + cc];
    __syncthreads();
    #pragma unroll
    for (int c = 0; c < 4; ++c) {
        int n = r + c * 8, k = cc;
        float xv = tl[k][n];
        unsigned short h, l;
        splitbf(xv, h, l);
        Wt[(size_t)(n0 + n) * 2 * K + k0 + k] = h;
        Wt[(size_t)(n0 + n) * 2 * K + K + k0 + k] = l;
    }
}

// ---------------- split-bf16 MFMA GEMM ----------------
// C[M,N] = A[M,K] @ B[K,N] with A2 [M,2K]=[Ah|Al], Bt2 [N,2K]=[Bh|Bl].
// 3-term: Ah.Bh + Al.Bh + Ah.Bl. Grid (M/128, N/64), 256 threads (4 waves).
template <int SIGMOID>
__global__ __launch_bounds__(256) void k_gemm_sp(const unsigned short* __restrict__ A2,
                                                 const unsigned short* __restrict__ Bt2,
                                                 float* __restrict__ C,
                                                 int K, int N) {
    __shared__ unsigned short As[128][64];
    __shared__ unsigned short Bs[64][64];
    const int tid = threadIdx.x;
    const int m0 = blockIdx.x * 128, n0 = blockIdx.y * 64;
    const int K2 = 2 * K;
    const int wid = tid >> 6, lane = tid & 63;
    const int wr = wid >> 1, wc = wid & 1;
    const int lr = lane & 15, lg = lane >> 4;

    const f32x4 zero4 = {0.f, 0.f, 0.f, 0.f};
    f32x4 acc[4][2];
    #pragma unroll
    for (int m = 0; m < 4; ++m)
        #pragma unroll
        for (int n = 0; n < 2; ++n) acc[m][n] = zero4;

    for (int s = 0; s < 3; ++s) {
        const int kaoff = (s == 1) ? K : 0;
        const int kboff = (s == 2) ? K : 0;
        for (int k0 = 0; k0 < K; k0 += 64) {
            #pragma unroll
            for (int c = 0; c < 4; ++c) {          // A tile: 128 rows x 8 granules
                int idx = c * 256 + tid;
                int row = idx >> 3, g = idx & 7;
                const unsigned short* src =
                    A2 + (size_t)(m0 + row) * K2 + kaoff + k0 + g * 8;
                int4 v = *(const int4*)src;
                *(int4*)&As[row][(g ^ (row & 7)) * 8] = v;
            }
            #pragma unroll
            for (int c = 0; c < 2; ++c) {          // B tile: 64 rows x 8 granules
                int idx = c * 256 + tid;
                int row = idx >> 3, g = idx & 7;
                const unsigned short* src =
                    Bt2 + (size_t)(n0 + row) * K2 + kboff + k0 + g * 8;
                int4 v = *(const int4*)src;
                *(int4*)&Bs[row][(g ^ (row & 7)) * 8] = v;
            }
            __syncthreads();
            #pragma unroll
            for (int ks = 0; ks < 2; ++ks) {
                const int kg = ks * 4 + lg;
                short8 a[4], b[2];
                #pragma unroll
                for (int m = 0; m < 4; ++m) {
                    int row = wr * 64 + m * 16 + lr;
                    a[m] = *(const short8*)&As[row][(kg ^ (row & 7)) * 8];
                }
                #pragma unroll
                for (int n = 0; n < 2; ++n) {
                    int row = wc * 32 + n * 16 + lr;
                    b[n] = *(const short8*)&Bs[row][(kg ^ (row & 7)) * 8];
                }
                #pragma unroll
                for (int m = 0; m < 4; ++m)
                    #pragma unroll
                    for (int n = 0; n < 2; ++n)
                        acc[m][n] = __builtin_amdgcn_mfma_f32_16x16x32_bf16(
                            a[m], b[n], acc[m][n], 0, 0, 0);
            }
            __syncthreads();
        }
    }
    #pragma unroll
    for (int m = 0; m < 4; ++m)
        #pragma unroll
        for (int n = 0; n < 2; ++n) {
            #pragma unroll
            for (int j = 0; j < 4; ++j) {
                int row = m0 + wr * 64 + m * 16 + lg * 4 + j;
                int col = n0 + wc * 32 + n * 16 + lr;
                float o = acc[m][n][j];
                if (SIGMOID) o = sigf(o);
                C[(size_t)row * N + col] = o;
            }
        }
}

// ---------------- GCN aggregate ----------------
template <int RELU, int SPLIT>
__global__ void k_gcn_agg(const float* __restrict__ v, const float* __restrict__ dinv,
                          const int* __restrict__ row_ptr, const int* __restrict__ csr_src,
                          const float* __restrict__ bias, float* __restrict__ outf,
                          unsigned short* __restrict__ outs, int D) {
    int d = blockIdx.x;
    int t = threadIdx.x;                         // blockDim == D
    float dd = dinv[d];
    float acc = dd * v[(size_t)d * D + t];
    int e0 = row_ptr[d], e1 = row_ptr[d + 1];
    for (int j = e0; j < e1; ++j) {
        int s = csr_src[j];
        acc += dinv[s] * v[(size_t)s * D + t];
    }
    float o = dd * acc + bias[t];
    if (RELU) o = fmaxf(o, 0.f);
    if (SPLIT) {
        unsigned short h, l;
        splitbf(o, h, l);
        outs[(size_t)d * 2 * D + t] = h;
        outs[(size_t)d * 2 * D + D + t] = l;
    } else {
        outf[(size_t)d * D + t] = o;
    }
}

// ---------------- GAT logits ----------------
__global__ void k_gat_logits(const float* __restrict__ h, const float* __restrict__ a_s,
                             const float* __restrict__ a_d, float* __restrict__ as_n,
                             float* __restrict__ ad_n, int D) {
    int n = blockIdx.x;
    int hd = threadIdx.x >> 6, lane = threadIdx.x & 63;   // block = 192
    float ss = 0.f, sd = 0.f;
    for (int dm = lane; dm < D; dm += 64) {
        float hv = h[(size_t)n * (NHEAD * D) + hd * D + dm];
        ss += hv * a_s[hd * D + dm];
        sd += hv * a_d[hd * D + dm];
    }
    #pragma unroll
    for (int off = 32; off; off >>= 1) {
        ss += __shfl_down(ss, off);
        sd += __shfl_down(sd, off);
    }
    if (lane == 0) { as_n[n * NHEAD + hd] = ss; ad_n[n * NHEAD + hd] = sd; }
}

// ---------------- GAT softmax weights (head-parallel, 2-pass over stored e) ----------
__global__ void k_gat_attn(const float* __restrict__ as_n, const float* __restrict__ ad_n,
                           const int* __restrict__ row_ptr, const int* __restrict__ csr_src,
                           float* __restrict__ w_csr, float* __restrict__ w_self) {
    int d = blockIdx.x;
    int hd = threadIdx.x >> 6, lane = threadIdx.x & 63;   // block = 192, wave = head
    int e0 = row_ptr[d], e1 = row_ptr[d + 1];
    float add = ad_n[d * NHEAD + hd];
    float eself = lrelu(as_n[d * NHEAD + hd] + add);
    float mx = eself;
    for (int j = e0 + lane; j < e1; j += 64) {
        float e = lrelu(as_n[csr_src[j] * NHEAD + hd] + add);
        w_csr[(size_t)j * NHEAD + hd] = e;
        mx = fmaxf(mx, e);
    }
    #pragma unroll
    for (int off = 32; off; off >>= 1) mx = fmaxf(mx, __shfl_xor(mx, off));
    float sm = (lane == 0) ? __expf(eself - mx) : 0.f;
    for (int j = e0 + lane; j < e1; j += 64)
        sm += __expf(w_csr[(size_t)j * NHEAD + hd] - mx);
    #pragma unroll
    for (int off = 32; off; off >>= 1) sm += __shfl_xor(sm, off);
    float inv = 1.f / sm;
    if (lane == 0) w_self[d * NHEAD + hd] = __expf(eself - mx) * inv;
    for (int j = e0 + lane; j < e1; j += 64)
        w_csr[(size_t)j * NHEAD + hd] =
            __expf(w_csr[(size_t)j * NHEAD + hd] - mx) * inv;
}

// ---------------- GAT layer1 aggregate (concat) + bias + relu -> split bf16 ----------
__global__ void k_gat_agg1(const float* __restrict__ h, const float* __restrict__ w_csr,
                           const float* __restrict__ w_self, const int* __restrict__ row_ptr,
                           const int* __restrict__ csr_src, const float* __restrict__ bias,
                           unsigned short* __restrict__ outs) {
    int d = blockIdx.x;
    int t = threadIdx.x;                          // block = 384
    int hd = t >> 7;
    float acc = w_self[d * NHEAD + hd] * h[(size_t)d * 384 + t];
    int e0 = row_ptr[d], e1 = row_ptr[d + 1];
    for (int j = e0; j < e1; ++j) {
        int s = csr_src[j];
        acc += w_csr[(size_t)j * NHEAD + hd] * h[(size_t)s * 384 + t];
    }
    float o = fmaxf(acc + bias[t], 0.f);
    unsigned short hh, ll;
    splitbf(o, hh, ll);
    outs[(size_t)d * 768 + t] = hh;
    outs[(size_t)d * 768 + 384 + t] = ll;
}

// ---------------- GAT layer2 aggregate + head-mean + bias ----------------
__global__ void k_gat_agg2(const float* __restrict__ h, const float* __restrict__ w_csr,
                           const float* __restrict__ w_self, const int* __restrict__ row_ptr,
                           const int* __restrict__ csr_src, const float* __restrict__ bias,
                           float* __restrict__ out) {
    int d = blockIdx.x;
    int t = threadIdx.x;                          // block = 64
    int e0 = row_ptr[d], e1 = row_ptr[d + 1];
    float tot = 0.f;
    for (int hd = 0; hd < NHEAD; ++hd) {
        float acc = w_self[d * NHEAD + hd] * h[(size_t)d * 192 + hd * 64 + t];
        for (int j = e0; j < e1; ++j) {
            int s = csr_src[j];
            acc += w_csr[(size_t)j * NHEAD + hd] * h[(size_t)s * 192 + hd * 64 + t];
        }
        tot += acc;
    }
    out[(size_t)d * 64 + t] = tot * (1.f / 3.f) + bias[t];
}

// ---------------- branch combine ----------------
template <int FIRST>
__global__ void k_combine(const float* __restrict__ mu, const float* __restrict__ lv,
                          const float* __restrict__ eps, float* __restrict__ mu_o,
                          float* __restrict__ lv_o, float* __restrict__ z_o) {
    int i = blockIdx.x * blockDim.x + threadIdx.x;      // NN*64 total
    float m = mu[i], l = lv[i];
    float z = m + eps[i] * __expf(l);
    if (FIRST) { mu_o[i] = m; lv_o[i] = l; z_o[i] = z; }
    else {
        mu_o[i] = fmaxf(mu_o[i], m);
        lv_o[i] = fmaxf(lv_o[i], l);
        z_o[i]  = fmaxf(z_o[i], z);
    }
}

extern "C" void kernel_launch(void* const* d_in, const int* in_sizes, int n_in,
                              void* d_out, int out_size, void* d_ws, size_t ws_size,
                              hipStream_t stream) {
    const float* x  = (const float*)d_in[0];
    const int*   ei = (const int*)d_in[1];
    const int E = in_sizes[1] / 2;
    const int* src = ei;
    const int* dst = ei + E;

    const float* gcn_W1  = (const float*)d_in[2];
    const float* gcn_b1  = (const float*)d_in[3];
    const float* gcn_Wmu = (const float*)d_in[4];
    const float* gcn_bmu = (const float*)d_in[5];
    const float* gcn_Wlv = (const float*)d_in[6];
    const float* gcn_blv = (const float*)d_in[7];
    const float* gat_W1  = (const float*)d_in[8];
    const float* gat_as1 = (const float*)d_in[9];
    const float* gat_ad1 = (const float*)d_in[10];
    const float* gat_b1  = (const float*)d_in[11];
    const float* gat_Wmu = (const float*)d_in[12];
    const float* gat_asmu= (const float*)d_in[13];
    const float* gat_admu= (const float*)d_in[14];
    const float* gat_bmu = (const float*)d_in[15];
    const float* gat_Wlv = (const float*)d_in[16];
    const float* gat_aslv= (const float*)d_in[17];
    const float* gat_adlv= (const float*)d_in[18];
    const float* gat_blv = (const float*)d_in[19];
    const float* eps_gcn = (const float*)d_in[20];
    const float* eps_gat = (const float*)d_in[21];

    // ---- workspace carve ----
    char* p = (char*)d_ws;
    auto alloc = [&](size_t bytes) {
        void* r = (void*)p;
        p += (bytes + 255) & ~(size_t)255;
        return r;
    };
    int*   cnt     = (int*)alloc((size_t)NN * 4);
    int*   cursor  = (int*)alloc((size_t)NN * 4);        // adjacent to cnt
    int*   row_ptr = (int*)alloc((size_t)(NN + 1) * 4);
    int*   csr_src = (int*)alloc((size_t)E * 4);
    float* dinv    = (float*)alloc((size_t)NN * 4);
    float* as_n    = (float*)alloc((size_t)NN * NHEAD * 4);
    float* ad_n    = (float*)alloc((size_t)NN * NHEAD * 4);
    float* w_self  = (float*)alloc((size_t)NN * NHEAD * 4);
    float* w_csr   = (float*)alloc((size_t)E * NHEAD * 4);
    unsigned short* x2      = (unsigned short*)alloc((size_t)NN * 1024 * 2);
    unsigned short* wt_gcn1 = (unsigned short*)alloc((size_t)2 * 128 * 1024 * 2);
    unsigned short* wt_gcnmu= (unsigned short*)alloc((size_t)2 * 64 * 256 * 2);
    unsigned short* wt_gcnlv= (unsigned short*)alloc((size_t)2 * 64 * 256 * 2);
    unsigned short* wt_gat1 = (unsigned short*)alloc((size_t)2 * 384 * 1024 * 2);
    unsigned short* wt_gatmu= (unsigned short*)alloc((size_t)2 * 192 * 768 * 2);
    unsigned short* wt_gatlv= (unsigned short*)alloc((size_t)2 * 192 * 768 * 2);
    float* xw1     = (float*)alloc((size_t)NN * 384 * 4);  // h2 aliases this
    unsigned short* h1s = (unsigned short*)alloc((size_t)NN * 768 * 2);
    float* mu_t    = (float*)alloc((size_t)NN * 64 * 4);
    float* lv_t    = (float*)alloc((size_t)NN * 64 * 4);
    float* zmax    = (float*)alloc((size_t)NN * 64 * 4);
    unsigned short* z2 = (unsigned short*)alloc((size_t)NN * 128 * 2);
    float* h2 = xw1;   // alias: xw1 dead when h2 written

    float* adj  = (float*)d_out;
    float* mu_o = adj + (size_t)NN * NN;
    float* lv_o = mu_o + (size_t)NN * 64;

    // ---- CSR build ----
    k_zero<<<(2 * NN + 255) / 256, 256, 0, stream>>>(cnt, 2 * NN);
    k_count<<<(E + 255) / 256, 256, 0, stream>>>(dst, cnt, E);
    k_dinv<<<(NN + 255) / 256, 256, 0, stream>>>(cnt, dinv);
    k_scan<<<1, 1024, 0, stream>>>(cnt, row_ptr);
    k_fill<<<(E + 255) / 256, 256, 0, stream>>>(src, dst, row_ptr, cursor, csr_src, E);

    // ---- precision prep ----
    k_split_x<<<NN * 512 / 4 / 256, 256, 0, stream>>>(x, x2);
    k_wsplitT<<<dim3(16, 4, 2), 256, 0, stream>>>(gcn_W1, wt_gcn1, 512, 128);
    k_wsplitT<<<dim3(4, 2, 2), 256, 0, stream>>>(gcn_Wmu, wt_gcnmu, 128, 64);
    k_wsplitT<<<dim3(4, 2, 2), 256, 0, stream>>>(gcn_Wlv, wt_gcnlv, 128, 64);
    k_wsplitT<<<dim3(16, 12, 2), 256, 0, stream>>>(gat_W1, wt_gat1, 512, 384);
    k_wsplitT<<<dim3(12, 6, 2), 256, 0, stream>>>(gat_Wmu, wt_gatmu, 384, 192);
    k_wsplitT<<<dim3(12, 6, 2), 256, 0, stream>>>(gat_Wlv, wt_gatlv, 384, 192);

    // ---- GCN branches ----
    for (int i = 0; i < 2; ++i) {
        k_gemm_sp<0><<<dim3(64, 2), 256, 0, stream>>>(x2, wt_gcn1 + (size_t)i * 128 * 1024,
                                                      xw1, 512, 128);
        k_gcn_agg<1, 1><<<NN, 128, 0, stream>>>(xw1, dinv, row_ptr, csr_src,
                                                gcn_b1 + i * 128, nullptr, h1s, 128);
        k_gemm_sp<0><<<dim3(64, 1), 256, 0, stream>>>(h1s, wt_gcnmu + (size_t)i * 64 * 256,
                                                      h2, 128, 64);
        k_gcn_agg<0, 0><<<NN, 64, 0, stream>>>(h2, dinv, row_ptr, csr_src,
                                               gcn_bmu + i * 64, mu_t, nullptr, 64);
        k_gemm_sp<0><<<dim3(64, 1), 256, 0, stream>>>(h1s, wt_gcnlv + (size_t)i * 64 * 256,
                                                      h2, 128, 64);
        k_gcn_agg<0, 0><<<NN, 64, 0, stream>>>(h2, dinv, row_ptr, csr_src,
                                               gcn_blv + i * 64, lv_t, nullptr, 64);
        if (i == 0)
            k_combine<1><<<NN * 64 / 256, 256, 0, stream>>>(mu_t, lv_t,
                eps_gcn + (size_t)i * NN * 64, mu_o, lv_o, zmax);
        else
            k_combine<0><<<NN * 64 / 256, 256, 0, stream>>>(mu_t, lv_t,
                eps_gcn + (size_t)i * NN * 64, mu_o, lv_o, zmax);
    }

    // ---- GAT branches ----
    for (int i = 0; i < 2; ++i) {
        k_gemm_sp<0><<<dim3(64, 6), 256, 0, stream>>>(x2, wt_gat1 + (size_t)i * 384 * 1024,
                                                      xw1, 512, 384);
        k_gat_logits<<<NN, 192, 0, stream>>>(xw1, gat_as1 + i * 384, gat_ad1 + i * 384,
                                             as_n, ad_n, 128);
        k_gat_attn<<<NN, 192, 0, stream>>>(as_n, ad_n, row_ptr, csr_src, w_csr, w_self);
        k_gat_agg1<<<NN, 384, 0, stream>>>(xw1, w_csr, w_self, row_ptr, csr_src,
                                           gat_b1 + i * 384, h1s);
        // mu head
        k_gemm_sp<0><<<dim3(64, 3), 256, 0, stream>>>(h1s, wt_gatmu + (size_t)i * 192 * 768,
                                                      h2, 384, 192);
        k_gat_logits<<<NN, 192, 0, stream>>>(h2, gat_asmu + i * 192, gat_admu + i * 192,
                                             as_n, ad_n, 64);
        k_gat_attn<<<NN, 192, 0, stream>>>(as_n, ad_n, row_ptr, csr_src, w_csr, w_self);
        k_gat_agg2<<<NN, 64, 0, stream>>>(h2, w_csr, w_self, row_ptr, csr_src,
                                          gat_bmu + i * 64, mu_t);
        // lv head
        k_gemm_sp<0><<<dim3(64, 3), 256, 0, stream>>>(h1s, wt_gatlv + (size_t)i * 192 * 768,
                                                      h2, 384, 192);
        k_gat_logits<<<NN, 192, 0, stream>>>(h2, gat_aslv + i * 192, gat_adlv + i * 192,
                                             as_n, ad_n, 64);
        k_gat_attn<<<NN, 192, 0, stream>>>(as_n, ad_n, row_ptr, csr_src, w_csr, w_self);
        k_gat_agg2<<<NN, 64, 0, stream>>>(h2, w_csr, w_self, row_ptr, csr_src,
                                          gat_blv + i * 64, lv_t);
        k_combine<0><<<NN * 64 / 256, 256, 0, stream>>>(mu_t, lv_t,
            eps_gat + (size_t)i * NN * 64, mu_o, lv_o, zmax);
    }

    // ---- adjacency: sigmoid(z z^T) via split-bf16 MFMA ----
    k_split_z<<<NN * 64 / 4 / 256, 256, 0, stream>>>(zmax, z2);
    k_gemm_sp<1><<<dim3(64, 128), 256, 0, stream>>>(z2, z2, adj, 64, 8192);
}

// Round 4
// 741.932 us; speedup vs baseline: 1.5330x; 1.2095x over previous
//
#include <hip/hip_runtime.h>
#include <hip/hip_bf16.h>
#include <math.h>
#include <stddef.h>

#define NN 8192
#define NHEAD 3
#define NEG_SLOPE 0.2f

typedef __attribute__((ext_vector_type(8))) short short8;
typedef __attribute__((ext_vector_type(4))) float f32x4;

__device__ __forceinline__ float lrelu(float x) { return x > 0.f ? x : NEG_SLOPE * x; }
__device__ __forceinline__ float sigf(float x) { return 1.f / (1.f + __expf(-x)); }

__device__ __forceinline__ void splitbf(float x, unsigned short& hu, unsigned short& lu) {
    __hip_bfloat16 h = __float2bfloat16(x);
    float hf = __bfloat162float(h);
    __hip_bfloat16 l = __float2bfloat16(x - hf);
    hu = *reinterpret_cast<unsigned short*>(&h);
    lu = *reinterpret_cast<unsigned short*>(&l);
}

// async global->LDS, 16B per lane; lds base must be wave-uniform
__device__ __forceinline__ void gll16(const unsigned short* g, unsigned short* l) {
    __builtin_amdgcn_global_load_lds(
        (const __attribute__((address_space(1))) unsigned int*)g,
        (__attribute__((address_space(3))) unsigned int*)l, 16, 0, 0);
}

// ---------------- CSR build ----------------
__global__ void k_zero(int* __restrict__ p, int n) {
    int i = blockIdx.x * blockDim.x + threadIdx.x;
    if (i < n) p[i] = 0;
}
__global__ void k_count(const int* __restrict__ dst, int* __restrict__ cnt, int E) {
    int i = blockIdx.x * blockDim.x + threadIdx.x;
    if (i < E) atomicAdd(&cnt[dst[i]], 1);
}
__global__ void k_dinv(const int* __restrict__ cnt, float* __restrict__ dinv) {
    int i = blockIdx.x * blockDim.x + threadIdx.x;
    if (i < NN) dinv[i] = rsqrtf((float)(cnt[i] + 1));
}
__global__ void k_scan(const int* __restrict__ cnt, int* __restrict__ row_ptr) {
    __shared__ int part[1024];
    int t = threadIdx.x;
    int base = t * 8;
    int loc[8];
    int s = 0;
    #pragma unroll
    for (int j = 0; j < 8; ++j) { loc[j] = s; s += cnt[base + j]; }
    part[t] = s;
    __syncthreads();
    for (int off = 1; off < 1024; off <<= 1) {
        int v = (t >= off) ? part[t - off] : 0;
        __syncthreads();
        part[t] += v;
        __syncthreads();
    }
    int pre = (t == 0) ? 0 : part[t - 1];
    #pragma unroll
    for (int j = 0; j < 8; ++j) row_ptr[base + j] = pre + loc[j];
    if (t == 1023) row_ptr[NN] = part[1023];
}
__global__ void k_fill(const int* __restrict__ src, const int* __restrict__ dst,
                       const int* __restrict__ row_ptr, int* __restrict__ cursor,
                       int* __restrict__ csr_src, int E) {
    int i = blockIdx.x * blockDim.x + threadIdx.x;
    if (i < E) {
        int d = dst[i];
        csr_src[row_ptr[d] + atomicAdd(&cursor[d], 1)] = src[i];
    }
}

// ---------------- split kernels ----------------
__global__ void k_split_x(const float* __restrict__ x, unsigned short* __restrict__ x2) {
    int i = blockIdx.x * 256 + threadIdx.x;     // over NN*512/4
    int m = i >> 7, k4 = (i & 127) * 4;
    float4 v = *(const float4*)(x + (size_t)m * 512 + k4);
    unsigned short h[4], l[4];
    splitbf(v.x, h[0], l[0]); splitbf(v.y, h[1], l[1]);
    splitbf(v.z, h[2], l[2]); splitbf(v.w, h[3], l[3]);
    ushort4 hv; hv.x = h[0]; hv.y = h[1]; hv.z = h[2]; hv.w = h[3];
    ushort4 lv; lv.x = l[0]; lv.y = l[1]; lv.z = l[2]; lv.w = l[3];
    *(ushort4*)&x2[(size_t)m * 1024 + k4] = hv;
    *(ushort4*)&x2[(size_t)m * 1024 + 512 + k4] = lv;
}

// W[z] [K,N] fp32 -> Wt rows (noff + z*noff_z + n), layout [2K] = [hi(K)|lo(K)]
__global__ void k_wsplitT(const float* __restrict__ W, unsigned short* __restrict__ Wt,
                          int K, int N, size_t wt_z_stride, int noff, int noff_z) {
    int b = blockIdx.z;
    W += (size_t)b * K * N;
    Wt += (size_t)b * wt_z_stride;
    int rowbase = noff + b * noff_z;
    int k0 = blockIdx.x * 32, n0 = blockIdx.y * 32;
    __shared__ float tl[32][33];
    int tid = threadIdx.x;
    int r = tid >> 5, cc = tid & 31;
    #pragma unroll
    for (int c = 0; c < 4; ++c)
        tl[r + c * 8][cc] = W[(size_t)(k0 + r + c * 8) * N + n0 + cc];
    __syncthreads();
    #pragma unroll
    for (int c = 0; c < 4; ++c) {
        int n = r + c * 8, k = cc;
        float xv = tl[k][n];
        unsigned short h, l;
        splitbf(xv, h, l);
        size_t ro = (size_t)(rowbase + n0 + n) * 2 * K;
        Wt[ro + k0 + k] = h;
        Wt[ro + K + k0 + k] = l;
    }
}

// ---------------- split-bf16 MFMA GEMM, global_load_lds staging ----------------
// A2 [M,2K-ish] hi at col k, lo at col K+k (row stride lda). B2 same with ldb.
// BM=128, BN=64, BK=64, 256 threads (4 waves), per-wave 64x32 out.
// stage tile ROWSx64 bf16, pre-swizzled source so ds_read is conflict-light.
template <int ROWS>
__device__ __forceinline__ void stage(const unsigned short* __restrict__ gbase, int lda,
                                      unsigned short* lds, int wid, int lane) {
    #pragma unroll
    for (int c = 0; c < ROWS / 32; ++c) {
        int chunk = c * 4 + wid;                // 1KB chunks
        int row = chunk * 8 + (lane >> 3);
        int g = (lane & 7) ^ (row & 7);
        gll16(gbase + (size_t)row * lda + g * 8, lds + chunk * 512);
    }
}
__device__ __forceinline__ short8 fragr(const unsigned short* lds, int row, int kg) {
    return *(const short8*)(lds + row * 64 + ((kg ^ (row & 7)) * 8));
}

template <int EPI>   // 0 = none, 1 = sigmoid
__global__ __launch_bounds__(256) void k_gemm2(
    const unsigned short* __restrict__ A2, size_t azs, int lda,
    const unsigned short* __restrict__ B2, size_t bzs, int ldb,
    float* __restrict__ C, size_t czs, int ldc, int K) {
    __shared__ __align__(16) unsigned short sAh[128 * 64];
    __shared__ __align__(16) unsigned short sAl[128 * 64];
    __shared__ __align__(16) unsigned short sBh[64 * 64];
    __shared__ __align__(16) unsigned short sBl[64 * 64];
    const int tid = threadIdx.x;
    const int wid = tid >> 6, lane = tid & 63;
    const int wr = wid >> 1, wc = wid & 1;
    const int lr = lane & 15, lg = lane >> 4;
    const int m0 = blockIdx.x * 128, n0 = blockIdx.y * 64;
    const int z = blockIdx.z;
    A2 += (size_t)z * azs;
    B2 += (size_t)z * bzs;
    C  += (size_t)z * czs;

    const f32x4 zero4 = {0.f, 0.f, 0.f, 0.f};
    f32x4 acc[4][2];
    #pragma unroll
    for (int m = 0; m < 4; ++m)
        #pragma unroll
        for (int n = 0; n < 2; ++n) acc[m][n] = zero4;

    for (int k0 = 0; k0 < K; k0 += 64) {
        stage<128>(A2 + (size_t)m0 * lda + k0,     lda, sAh, wid, lane);
        stage<128>(A2 + (size_t)m0 * lda + K + k0, lda, sAl, wid, lane);
        stage<64> (B2 + (size_t)n0 * ldb + k0,     ldb, sBh, wid, lane);
        stage<64> (B2 + (size_t)n0 * ldb + K + k0, ldb, sBl, wid, lane);
        __syncthreads();
        #pragma unroll
        for (int ks = 0; ks < 2; ++ks) {
            const int kg = ks * 4 + lg;
            short8 ah[4], al[4], bh[2], bl[2];
            #pragma unroll
            for (int m = 0; m < 4; ++m) {
                int row = wr * 64 + m * 16 + lr;
                ah[m] = fragr(sAh, row, kg);
                al[m] = fragr(sAl, row, kg);
            }
            #pragma unroll
            for (int n = 0; n < 2; ++n) {
                int row = wc * 32 + n * 16 + lr;
                bh[n] = fragr(sBh, row, kg);
                bl[n] = fragr(sBl, row, kg);
            }
            #pragma unroll
            for (int m = 0; m < 4; ++m)
                #pragma unroll
                for (int n = 0; n < 2; ++n) {
                    acc[m][n] = __builtin_amdgcn_mfma_f32_16x16x32_bf16(ah[m], bh[n], acc[m][n], 0, 0, 0);
                    acc[m][n] = __builtin_amdgcn_mfma_f32_16x16x32_bf16(al[m], bh[n], acc[m][n], 0, 0, 0);
                    acc[m][n] = __builtin_amdgcn_mfma_f32_16x16x32_bf16(ah[m], bl[n], acc[m][n], 0, 0, 0);
                }
        }
        __syncthreads();
    }
    #pragma unroll
    for (int m = 0; m < 4; ++m)
        #pragma unroll
        for (int n = 0; n < 2; ++n)
            #pragma unroll
            for (int j = 0; j < 4; ++j) {
                int row = m0 + wr * 64 + m * 16 + lg * 4 + j;
                int col = n0 + wc * 32 + n * 16 + lr;
                float o = acc[m][n][j];
                if (EPI == 1) o = sigf(o);
                C[(size_t)row * ldc + col] = o;
            }
}

// ---------------- GCN layer1 aggregate: h = relu(Agg(xw)+b1), both branches (256 cols) ----
// xw row stride 256 (GCN GEMM writes ldc=256)
__global__ void k_gcn_a1(const float* __restrict__ xw, const float* __restrict__ dinv,
                         const int* __restrict__ rp, const int* __restrict__ cs,
                         const float* __restrict__ b1, float* __restrict__ h) {
    int d = blockIdx.x;
    int t = threadIdx.x;                         // 256
    float dd = dinv[d];
    float acc = dd * xw[(size_t)d * 256 + t];
    int e0 = rp[d], e1 = rp[d + 1];
    for (int j = e0; j < e1; ++j) {
        int s = cs[j];
        acc += dinv[s] * xw[(size_t)s * 256 + t];
    }
    h[(size_t)d * 256 + t] = fmaxf(dd * acc + b1[t], 0.f);
}

// ---------------- GCN second aggregate: hA = Agg(h) -> split bf16 per branch ----------
__global__ void k_gcn_a2(const float* __restrict__ h, const float* __restrict__ dinv,
                         const int* __restrict__ rp, const int* __restrict__ cs,
                         unsigned short* __restrict__ hA2) {
    int d = blockIdx.x;
    int t = threadIdx.x;                         // 256
    float dd = dinv[d];
    float acc = dd * h[(size_t)d * 256 + t];
    int e0 = rp[d], e1 = rp[d + 1];
    for (int j = e0; j < e1; ++j) {
        int s = cs[j];
        acc += dinv[s] * h[(size_t)s * 256 + t];
    }
    float o = dd * acc;
    int br = t >> 7, c = t & 127;
    unsigned short hh, ll;
    splitbf(o, hh, ll);
    hA2[(size_t)d * 512 + br * 256 + c] = hh;
    hA2[(size_t)d * 512 + br * 256 + 128 + c] = ll;
}

// ---------------- GAT layer1 logits (z = branch) ----------------
__global__ void k_gat_log1(const float* __restrict__ xw, const float* __restrict__ a_s,
                           const float* __restrict__ a_d, float* __restrict__ as_n,
                           float* __restrict__ ad_n) {
    int br = blockIdx.z;
    int n = blockIdx.x;
    int hd = threadIdx.x >> 6, lane = threadIdx.x & 63;   // block 192
    const float* hp = xw + (size_t)n * 768 + br * 384 + hd * 128;
    const float* av = a_s + br * 384 + hd * 128;
    const float* dv = a_d + br * 384 + hd * 128;
    float ss = 0.f, sd = 0.f;
    #pragma unroll
    for (int c = 0; c < 2; ++c) {
        float hv = hp[lane + c * 64];
        ss += hv * av[lane + c * 64];
        sd += hv * dv[lane + c * 64];
    }
    #pragma unroll
    for (int off = 32; off; off >>= 1) {
        ss += __shfl_down(ss, off);
        sd += __shfl_down(sd, off);
    }
    if (lane == 0) {
        as_n[(size_t)br * NN * 3 + n * 3 + hd] = ss;
        ad_n[(size_t)br * NN * 3 + n * 3 + hd] = sd;
    }
}

// ---------------- GAT layer2 logits (z = branch*2 + mtype) ----------------
__global__ void k_gat_log2(const float* __restrict__ h2g, const float* __restrict__ asmu,
                           const float* __restrict__ aslv, const float* __restrict__ admu,
                           const float* __restrict__ adlv, float* __restrict__ as_n,
                           float* __restrict__ ad_n) {
    int zz = blockIdx.z;
    int br = zz >> 1, mt = zz & 1;
    int n = blockIdx.x;
    int hd = threadIdx.x >> 6, lane = threadIdx.x & 63;   // block 192
    const float* hp = h2g + (size_t)br * NN * 384 + (size_t)n * 384 + mt * 192 + hd * 64;
    const float* av = (mt ? aslv : asmu) + br * 192 + hd * 64;
    const float* dv = (mt ? adlv : admu) + br * 192 + hd * 64;
    float hv = hp[lane];
    float ss = hv * av[lane];
    float sd = hv * dv[lane];
    #pragma unroll
    for (int off = 32; off; off >>= 1) {
        ss += __shfl_down(ss, off);
        sd += __shfl_down(sd, off);
    }
    if (lane == 0) {
        as_n[(size_t)zz * NN * 3 + n * 3 + hd] = ss;
        ad_n[(size_t)zz * NN * 3 + n * 3 + hd] = sd;
    }
}

// ---------------- GAT softmax weights (z batched, wave per head) ----------------
__global__ void k_gat_attn(const float* __restrict__ as_n, const float* __restrict__ ad_n,
                           const int* __restrict__ rp, const int* __restrict__ cs,
                           float* __restrict__ w_csr, float* __restrict__ w_self, int E3) {
    int zz = blockIdx.z;
    as_n += (size_t)zz * NN * 3;
    ad_n += (size_t)zz * NN * 3;
    w_csr += (size_t)zz * E3;
    w_self += (size_t)zz * NN * 3;
    int d = blockIdx.x;
    int hd = threadIdx.x >> 6, lane = threadIdx.x & 63;   // block 192
    int e0 = rp[d], e1 = rp[d + 1];
    float add = ad_n[d * 3 + hd];
    float eself = lrelu(as_n[d * 3 + hd] + add);
    float mx = eself;
    for (int j = e0 + lane; j < e1; j += 64) {
        float e = lrelu(as_n[cs[j] * 3 + hd] + add);
        w_csr[(size_t)j * 3 + hd] = e;
        mx = fmaxf(mx, e);
    }
    #pragma unroll
    for (int off = 32; off; off >>= 1) mx = fmaxf(mx, __shfl_xor(mx, off));
    float sm = (lane == 0) ? __expf(eself - mx) : 0.f;
    for (int j = e0 + lane; j < e1; j += 64)
        sm += __expf(w_csr[(size_t)j * 3 + hd] - mx);
    #pragma unroll
    for (int off = 32; off; off >>= 1) sm += __shfl_xor(sm, off);
    float inv = 1.f / sm;
    if (lane == 0) w_self[d * 3 + hd] = __expf(eself - mx) * inv;
    for (int j = e0 + lane; j < e1; j += 64)
        w_csr[(size_t)j * 3 + hd] = __expf(w_csr[(size_t)j * 3 + hd] - mx) * inv;
}

// ---------------- GAT layer1 aggregate, both branches (768 threads) ----------------
__global__ void k_gat_agg1(const float* __restrict__ xw, const float* __restrict__ w_csr,
                           const float* __restrict__ w_self, const int* __restrict__ rp,
                           const int* __restrict__ cs, const float* __restrict__ b1,
                           unsigned short* __restrict__ h1s, int E3) {
    int d = blockIdx.x;
    int t = threadIdx.x;                          // 768
    int br = t >= 384 ? 1 : 0;
    int c = t - br * 384;
    int hd = c >> 7;
    const float* wc = w_csr + (size_t)br * E3;
    float ws = w_self[(size_t)br * NN * 3 + d * 3 + hd];
    float acc = ws * xw[(size_t)d * 768 + t];
    int e0 = rp[d], e1 = rp[d + 1];
    for (int j = e0; j < e1; ++j) {
        int s = cs[j];
        acc += wc[(size_t)j * 3 + hd] * xw[(size_t)s * 768 + t];
    }
    float o = fmaxf(acc + b1[t], 0.f);
    unsigned short hh, ll;
    splitbf(o, hh, ll);
    h1s[(size_t)d * 1536 + br * 768 + c] = hh;
    h1s[(size_t)d * 1536 + br * 768 + 384 + c] = ll;
}

// ---------------- GAT layer2 aggregate, mu+lv together (z = branch, 384 threads) ------
__global__ void k_gat_agg2(const float* __restrict__ h2g, const float* __restrict__ w_csr,
                           const float* __restrict__ w_self, const int* __restrict__ rp,
                           const int* __restrict__ cs, const float* __restrict__ bmu,
                           const float* __restrict__ blv, float* __restrict__ mt_gat, int E3) {
    int br = blockIdx.z;
    int d = blockIdx.x;
    int t = threadIdx.x;                          // 384: [mu 192 | lv 192]
    int mt = t >= 192 ? 1 : 0;
    int c = t - mt * 192;
    int hd = c >> 6, dd = c & 63;
    const float* hp = h2g + (size_t)br * NN * 384;
    const float* wc = w_csr + (size_t)(br * 2 + mt) * E3;
    float ws = w_self[(size_t)(br * 2 + mt) * NN * 3 + d * 3 + hd];
    float acc = ws * hp[(size_t)d * 384 + t];
    int e0 = rp[d], e1 = rp[d + 1];
    for (int j = e0; j < e1; ++j) {
        int s = cs[j];
        acc += wc[(size_t)j * 3 + hd] * hp[(size_t)s * 384 + t];
    }
    __shared__ float red[384];
    red[t] = acc;
    __syncthreads();
    if (c < 64) {
        float tot = red[mt * 192 + dd] + red[mt * 192 + 64 + dd] + red[mt * 192 + 128 + dd];
        const float* bias = mt ? blv : bmu;
        float o = tot * (1.f / 3.f) + bias[br * 64 + dd];
        mt_gat[((size_t)(br * 2 + mt) * NN + d) * 64 + dd] = o;
    }
}

// ---------------- finalize: bias, z, 4-way max, outputs + split z2 ----------------
__global__ void k_finalize(const float* __restrict__ muv_gcn, const float* __restrict__ gcn_bmu,
                           const float* __restrict__ gcn_blv, const float* __restrict__ mt_gat,
                           const float* __restrict__ eps_gcn, const float* __restrict__ eps_gat,
                           float* __restrict__ mu_o, float* __restrict__ lv_o,
                           unsigned short* __restrict__ z2) {
    int i = blockIdx.x * 256 + threadIdx.x;       // NN*64
    int d = i >> 6, c = i & 63;
    const size_t NN64 = (size_t)NN * 64;
    float mu, lv, zm;
    {
        float m = muv_gcn[(size_t)d * 128 + c] + gcn_bmu[c];
        float l = muv_gcn[(size_t)d * 128 + 64 + c] + gcn_blv[c];
        float z = m + eps_gcn[i] * __expf(l);
        mu = m; lv = l; zm = z;
    }
    {
        float m = muv_gcn[NN64 * 2 + (size_t)d * 128 + c] + gcn_bmu[64 + c];
        float l = muv_gcn[NN64 * 2 + (size_t)d * 128 + 64 + c] + gcn_blv[64 + c];
        float z = m + eps_gcn[NN64 + i] * __expf(l);
        mu = fmaxf(mu, m); lv = fmaxf(lv, l); zm = fmaxf(zm, z);
    }
    #pragma unroll
    for (int br = 0; br < 2; ++br) {
        float m = mt_gat[(size_t)(br * 2 + 0) * NN64 + i];
        float l = mt_gat[(size_t)(br * 2 + 1) * NN64 + i];
        float z = m + eps_gat[(size_t)br * NN64 + i] * __expf(l);
        mu = fmaxf(mu, m); lv = fmaxf(lv, l); zm = fmaxf(zm, z);
    }
    mu_o[i] = mu;
    lv_o[i] = lv;
    unsigned short hh, ll;
    splitbf(zm, hh, ll);
    z2[(size_t)d * 128 + c] = hh;
    z2[(size_t)d * 128 + 64 + c] = ll;
}

extern "C" void kernel_launch(void* const* d_in, const int* in_sizes, int n_in,
                              void* d_out, int out_size, void* d_ws, size_t ws_size,
                              hipStream_t stream) {
    const float* x  = (const float*)d_in[0];
    const int*   ei = (const int*)d_in[1];
    const int E = in_sizes[1] / 2;
    const int E3 = E * 3;
    const int* src = ei;
    const int* dst = ei + E;

    const float* gcn_W1  = (const float*)d_in[2];
    const float* gcn_b1  = (const float*)d_in[3];
    const float* gcn_Wmu = (const float*)d_in[4];
    const float* gcn_bmu = (const float*)d_in[5];
    const float* gcn_Wlv = (const float*)d_in[6];
    const float* gcn_blv = (const float*)d_in[7];
    const float* gat_W1  = (const float*)d_in[8];
    const float* gat_as1 = (const float*)d_in[9];
    const float* gat_ad1 = (const float*)d_in[10];
    const float* gat_b1  = (const float*)d_in[11];
    const float* gat_Wmu = (const float*)d_in[12];
    const float* gat_asmu= (const float*)d_in[13];
    const float* gat_admu= (const float*)d_in[14];
    const float* gat_bmu = (const float*)d_in[15];
    const float* gat_Wlv = (const float*)d_in[16];
    const float* gat_aslv= (const float*)d_in[17];
    const float* gat_adlv= (const float*)d_in[18];
    const float* gat_blv = (const float*)d_in[19];
    const float* eps_gcn = (const float*)d_in[20];
    const float* eps_gat = (const float*)d_in[21];

    // ---- workspace carve ----
    char* p = (char*)d_ws;
    auto alloc = [&](size_t bytes) {
        void* r = (void*)p;
        p += (bytes + 255) & ~(size_t)255;
        return r;
    };
    int*   cnt     = (int*)alloc((size_t)NN * 4);
    int*   cursor  = (int*)alloc((size_t)NN * 4);
    int*   row_ptr = (int*)alloc((size_t)(NN + 1) * 4);
    int*   csr_src = (int*)alloc((size_t)E * 4);
    float* dinv    = (float*)alloc((size_t)NN * 4);
    float* as_n1   = (float*)alloc((size_t)2 * NN * 3 * 4);
    float* ad_n1   = (float*)alloc((size_t)2 * NN * 3 * 4);
    float* wself1  = (float*)alloc((size_t)2 * NN * 3 * 4);
    float* wcsr1   = (float*)alloc((size_t)2 * E3 * 4);
    float* as_n2   = (float*)alloc((size_t)4 * NN * 3 * 4);
    float* ad_n2   = (float*)alloc((size_t)4 * NN * 3 * 4);
    float* wself2  = (float*)alloc((size_t)4 * NN * 3 * 4);
    float* wcsr2   = (float*)alloc((size_t)4 * E3 * 4);
    unsigned short* x2       = (unsigned short*)alloc((size_t)NN * 1024 * 2);
    unsigned short* wt_gcn1  = (unsigned short*)alloc((size_t)256 * 1024 * 2);
    unsigned short* wt_gcnmuv= (unsigned short*)alloc((size_t)2 * 128 * 256 * 2);
    unsigned short* wt_gat1  = (unsigned short*)alloc((size_t)768 * 1024 * 2);
    unsigned short* wt_gatmuv= (unsigned short*)alloc((size_t)2 * 384 * 768 * 2);
    float* xw      = (float*)alloc((size_t)NN * 768 * 4);   // GCN uses ld 256
    float* h_gcn   = (float*)alloc((size_t)NN * 256 * 4);
    unsigned short* hA2 = (unsigned short*)alloc((size_t)NN * 512 * 2);
    float* muv_gcn = (float*)alloc((size_t)2 * NN * 128 * 4);
    unsigned short* h1s = (unsigned short*)alloc((size_t)NN * 1536 * 2);
    float* h2g     = (float*)alloc((size_t)2 * NN * 384 * 4);
    float* mt_gat  = (float*)alloc((size_t)4 * NN * 64 * 4);
    unsigned short* z2 = (unsigned short*)alloc((size_t)NN * 128 * 2);

    float* adj  = (float*)d_out;
    float* mu_o = adj + (size_t)NN * NN;
    float* lv_o = mu_o + (size_t)NN * 64;

    // ---- CSR build ----
    k_zero<<<(2 * NN + 255) / 256, 256, 0, stream>>>(cnt, 2 * NN);
    k_count<<<(E + 255) / 256, 256, 0, stream>>>(dst, cnt, E);
    k_dinv<<<(NN + 255) / 256, 256, 0, stream>>>(cnt, dinv);
    k_scan<<<1, 1024, 0, stream>>>(cnt, row_ptr);
    k_fill<<<(E + 255) / 256, 256, 0, stream>>>(src, dst, row_ptr, cursor, csr_src, E);

    // ---- precision prep ----
    k_split_x<<<NN * 512 / 4 / 256, 256, 0, stream>>>(x, x2);
    k_wsplitT<<<dim3(16, 4, 2), 256, 0, stream>>>(gcn_W1, wt_gcn1, 512, 128, 0, 0, 128);
    k_wsplitT<<<dim3(4, 2, 2), 256, 0, stream>>>(gcn_Wmu, wt_gcnmuv, 128, 64,
                                                 (size_t)128 * 256, 0, 0);
    k_wsplitT<<<dim3(4, 2, 2), 256, 0, stream>>>(gcn_Wlv, wt_gcnmuv, 128, 64,
                                                 (size_t)128 * 256, 64, 0);
    k_wsplitT<<<dim3(16, 12, 2), 256, 0, stream>>>(gat_W1, wt_gat1, 512, 384, 0, 0, 384);
    k_wsplitT<<<dim3(12, 6, 2), 256, 0, stream>>>(gat_Wmu, wt_gatmuv, 384, 192,
                                                  (size_t)384 * 768, 0, 0);
    k_wsplitT<<<dim3(12, 6, 2), 256, 0, stream>>>(gat_Wlv, wt_gatmuv, 384, 192,
                                                  (size_t)384 * 768, 192, 0);

    // ---- GCN (both branches batched) ----
    // g1: xw[:, :256] = x2 @ wt_gcn1  (M=8192, K=512, N=256), ldc=256
    k_gemm2<0><<<dim3(64, 4, 1), 256, 0, stream>>>(x2, 0, 1024, wt_gcn1, 0, 1024,
                                                   xw, 0, 256, 512);
    k_gcn_a1<<<NN, 256, 0, stream>>>(xw, dinv, row_ptr, csr_src, gcn_b1, h_gcn);
    k_gcn_a2<<<NN, 256, 0, stream>>>(h_gcn, dinv, row_ptr, csr_src, hA2);
    // g2: muv[z] = hA2[z] @ wt_gcnmuv[z]  (K=128, N=128), z=branch
    k_gemm2<0><<<dim3(64, 2, 2), 256, 0, stream>>>(hA2, 256, 512, wt_gcnmuv,
                                                   (size_t)128 * 256, 256,
                                                   muv_gcn, (size_t)NN * 128, 128, 128);

    // ---- GAT (both branches batched) ----
    // G1: xw = x2 @ wt_gat1  (K=512, N=768)
    k_gemm2<0><<<dim3(64, 12, 1), 256, 0, stream>>>(x2, 0, 1024, wt_gat1, 0, 1024,
                                                    xw, 0, 768, 512);
    k_gat_log1<<<dim3(NN, 1, 2), 192, 0, stream>>>(xw, gat_as1, gat_ad1, as_n1, ad_n1);
    k_gat_attn<<<dim3(NN, 1, 2), 192, 0, stream>>>(as_n1, ad_n1, row_ptr, csr_src,
                                                   wcsr1, wself1, E3);
    k_gat_agg1<<<NN, 768, 0, stream>>>(xw, wcsr1, wself1, row_ptr, csr_src, gat_b1, h1s, E3);
    // G2: h2g[z] = h1s[z] @ wt_gatmuv[z]  (K=384, N=384), z=branch
    k_gemm2<0><<<dim3(64, 6, 2), 256, 0, stream>>>(h1s, 768, 1536, wt_gatmuv,
                                                   (size_t)384 * 768, 768,
                                                   h2g, (size_t)NN * 384, 384, 384);
    k_gat_log2<<<dim3(NN, 1, 4), 192, 0, stream>>>(h2g, gat_asmu, gat_aslv, gat_admu,
                                                   gat_adlv, as_n2, ad_n2);
    k_gat_attn<<<dim3(NN, 1, 4), 192, 0, stream>>>(as_n2, ad_n2, row_ptr, csr_src,
                                                   wcsr2, wself2, E3);
    k_gat_agg2<<<dim3(NN, 1, 2), 384, 0, stream>>>(h2g, wcsr2, wself2, row_ptr, csr_src,
                                                   gat_bmu, gat_blv, mt_gat, E3);

    // ---- finalize + adjacency ----
    k_finalize<<<NN * 64 / 256, 256, 0, stream>>>(muv_gcn, gcn_bmu, gcn_blv, mt_gat,
                                                  eps_gcn, eps_gat, mu_o, lv_o, z2);
    k_gemm2<1><<<dim3(64, 128, 1), 256, 0, stream>>>(z2, 0, 128, z2, 0, 128,
                                                     adj, 0, NN, 64);
}

// Round 5
// 390.189 us; speedup vs baseline: 2.9149x; 1.9015x over previous
//
#include <hip/hip_runtime.h>
#include <hip/hip_bf16.h>
#include <math.h>
#include <stddef.h>

#define NN 8192
#define NHEAD 3
#define NEG_SLOPE 0.2f

typedef __attribute__((ext_vector_type(8))) short short8;
typedef __attribute__((ext_vector_type(4))) float f32x4;

__device__ __forceinline__ float lrelu(float x) { return x > 0.f ? x : NEG_SLOPE * x; }
__device__ __forceinline__ float sigf(float x) { return 1.f / (1.f + __expf(-x)); }

__device__ __forceinline__ void splitbf(float x, unsigned short& hu, unsigned short& lu) {
    __hip_bfloat16 h = __float2bfloat16(x);
    float hf = __bfloat162float(h);
    __hip_bfloat16 l = __float2bfloat16(x - hf);
    hu = *reinterpret_cast<unsigned short*>(&h);
    lu = *reinterpret_cast<unsigned short*>(&l);
}
__device__ __forceinline__ unsigned short bfr(float x) {
    __hip_bfloat16 h = __float2bfloat16(x);
    return *reinterpret_cast<unsigned short*>(&h);
}
__device__ __forceinline__ unsigned int pack2(float a, float b) {
    return (unsigned int)bfr(a) | ((unsigned int)bfr(b) << 16);
}
__device__ __forceinline__ float2 unpk(unsigned int v) {
    unsigned int lo = v << 16;
    unsigned int hi = v & 0xffff0000u;
    float2 r;
    r.x = *reinterpret_cast<float*>(&lo);
    r.y = *reinterpret_cast<float*>(&hi);
    return r;
}
__device__ __forceinline__ float bf2f(unsigned short u) {
    unsigned int b = (unsigned int)u << 16;
    return *reinterpret_cast<float*>(&b);
}

// async global->LDS, 16B per lane; lds base must be wave-uniform
__device__ __forceinline__ void gll16(const unsigned short* g, unsigned short* l) {
    __builtin_amdgcn_global_load_lds(
        (const __attribute__((address_space(1))) unsigned int*)g,
        (__attribute__((address_space(3))) unsigned int*)l, 16, 0, 0);
}

// ---------------- CSR build ----------------
__global__ void k_zero(int* __restrict__ p, int n) {
    int i = blockIdx.x * blockDim.x + threadIdx.x;
    if (i < n) p[i] = 0;
}
__global__ void k_count(const int* __restrict__ dst, int* __restrict__ cnt, int E) {
    int i = blockIdx.x * blockDim.x + threadIdx.x;
    if (i < E) atomicAdd(&cnt[dst[i]], 1);
}
__global__ void k_dinv(const int* __restrict__ cnt, float* __restrict__ dinv) {
    int i = blockIdx.x * blockDim.x + threadIdx.x;
    if (i < NN) dinv[i] = rsqrtf((float)(cnt[i] + 1));
}
__global__ void k_scan(const int* __restrict__ cnt, int* __restrict__ row_ptr) {
    __shared__ int part[1024];
    int t = threadIdx.x;
    int base = t * 8;
    int loc[8];
    int s = 0;
    #pragma unroll
    for (int j = 0; j < 8; ++j) { loc[j] = s; s += cnt[base + j]; }
    part[t] = s;
    __syncthreads();
    for (int off = 1; off < 1024; off <<= 1) {
        int v = (t >= off) ? part[t - off] : 0;
        __syncthreads();
        part[t] += v;
        __syncthreads();
    }
    int pre = (t == 0) ? 0 : part[t - 1];
    #pragma unroll
    for (int j = 0; j < 8; ++j) row_ptr[base + j] = pre + loc[j];
    if (t == 1023) row_ptr[NN] = part[1023];
}
__global__ void k_fill(const int* __restrict__ src, const int* __restrict__ dst,
                       const int* __restrict__ row_ptr, int* __restrict__ cursor,
                       int* __restrict__ csr_src, int E) {
    int i = blockIdx.x * blockDim.x + threadIdx.x;
    if (i < E) {
        int d = dst[i];
        csr_src[row_ptr[d] + atomicAdd(&cursor[d], 1)] = src[i];
    }
}

// ---------------- split kernels ----------------
__global__ void k_split_x(const float* __restrict__ x, unsigned short* __restrict__ x2) {
    int i = blockIdx.x * 256 + threadIdx.x;     // over NN*512/4
    int m = i >> 7, k4 = (i & 127) * 4;
    float4 v = *(const float4*)(x + (size_t)m * 512 + k4);
    unsigned short h[4], l[4];
    splitbf(v.x, h[0], l[0]); splitbf(v.y, h[1], l[1]);
    splitbf(v.z, h[2], l[2]); splitbf(v.w, h[3], l[3]);
    ushort4 hv; hv.x = h[0]; hv.y = h[1]; hv.z = h[2]; hv.w = h[3];
    ushort4 lv; lv.x = l[0]; lv.y = l[1]; lv.z = l[2]; lv.w = l[3];
    *(ushort4*)&x2[(size_t)m * 1024 + k4] = hv;
    *(ushort4*)&x2[(size_t)m * 1024 + 512 + k4] = lv;
}

// W[z] [K,N] fp32 -> Wt rows (noff + z*noff_z + n), layout [2K] = [hi(K)|lo(K)]
__global__ void k_wsplitT(const float* __restrict__ W, unsigned short* __restrict__ Wt,
                          int K, int N, size_t wt_z_stride, int noff, int noff_z) {
    int b = blockIdx.z;
    W += (size_t)b * K * N;
    Wt += (size_t)b * wt_z_stride;
    int rowbase = noff + b * noff_z;
    int k0 = blockIdx.x * 32, n0 = blockIdx.y * 32;
    __shared__ float tl[32][33];
    int tid = threadIdx.x;
    int r = tid >> 5, cc = tid & 31;
    #pragma unroll
    for (int c = 0; c < 4; ++c)
        tl[r + c * 8][cc] = W[(size_t)(k0 + r + c * 8) * N + n0 + cc];
    __syncthreads();
    #pragma unroll
    for (int c = 0; c < 4; ++c) {
        int n = r + c * 8, k = cc;
        float xv = tl[k][n];
        unsigned short h, l;
        splitbf(xv, h, l);
        size_t ro = (size_t)(rowbase + n0 + n) * 2 * K;
        Wt[ro + k0 + k] = h;
        Wt[ro + K + k0 + k] = l;
    }
}

// ---------------- split-bf16 MFMA GEMM, global_load_lds staging ----------------
template <int ROWS>
__device__ __forceinline__ void stage(const unsigned short* __restrict__ gbase, int lda,
                                      unsigned short* lds, int wid, int lane) {
    #pragma unroll
    for (int c = 0; c < ROWS / 32; ++c) {
        int chunk = c * 4 + wid;                // 1KB chunks
        int row = chunk * 8 + (lane >> 3);
        int g = (lane & 7) ^ (row & 7);
        gll16(gbase + (size_t)row * lda + g * 8, lds + chunk * 512);
    }
}
__device__ __forceinline__ short8 fragr(const unsigned short* lds, int row, int kg) {
    return *(const short8*)(lds + row * 64 + ((kg ^ (row & 7)) * 8));
}

template <int EPI>   // 0 = fp32, 1 = fp32+sigmoid, 2 = bf16 out
__global__ __launch_bounds__(256) void k_gemm2(
    const unsigned short* __restrict__ A2, size_t azs, int lda,
    const unsigned short* __restrict__ B2, size_t bzs, int ldb,
    void* __restrict__ Cv, size_t czs, int ldc, int K) {
    __shared__ __align__(16) unsigned short sAh[128 * 64];
    __shared__ __align__(16) unsigned short sAl[128 * 64];
    __shared__ __align__(16) unsigned short sBh[64 * 64];
    __shared__ __align__(16) unsigned short sBl[64 * 64];
    const int tid = threadIdx.x;
    const int wid = tid >> 6, lane = tid & 63;
    const int wr = wid >> 1, wc = wid & 1;
    const int lr = lane & 15, lg = lane >> 4;
    const int m0 = blockIdx.x * 128, n0 = blockIdx.y * 64;
    const int z = blockIdx.z;
    A2 += (size_t)z * azs;
    B2 += (size_t)z * bzs;

    const f32x4 zero4 = {0.f, 0.f, 0.f, 0.f};
    f32x4 acc[4][2];
    #pragma unroll
    for (int m = 0; m < 4; ++m)
        #pragma unroll
        for (int n = 0; n < 2; ++n) acc[m][n] = zero4;

    for (int k0 = 0; k0 < K; k0 += 64) {
        stage<128>(A2 + (size_t)m0 * lda + k0,     lda, sAh, wid, lane);
        stage<128>(A2 + (size_t)m0 * lda + K + k0, lda, sAl, wid, lane);
        stage<64> (B2 + (size_t)n0 * ldb + k0,     ldb, sBh, wid, lane);
        stage<64> (B2 + (size_t)n0 * ldb + K + k0, ldb, sBl, wid, lane);
        __syncthreads();
        #pragma unroll
        for (int ks = 0; ks < 2; ++ks) {
            const int kg = ks * 4 + lg;
            short8 ah[4], al[4], bh[2], bl[2];
            #pragma unroll
            for (int m = 0; m < 4; ++m) {
                int row = wr * 64 + m * 16 + lr;
                ah[m] = fragr(sAh, row, kg);
                al[m] = fragr(sAl, row, kg);
            }
            #pragma unroll
            for (int n = 0; n < 2; ++n) {
                int row = wc * 32 + n * 16 + lr;
                bh[n] = fragr(sBh, row, kg);
                bl[n] = fragr(sBl, row, kg);
            }
            #pragma unroll
            for (int m = 0; m < 4; ++m)
                #pragma unroll
                for (int n = 0; n < 2; ++n) {
                    acc[m][n] = __builtin_amdgcn_mfma_f32_16x16x32_bf16(ah[m], bh[n], acc[m][n], 0, 0, 0);
                    acc[m][n] = __builtin_amdgcn_mfma_f32_16x16x32_bf16(al[m], bh[n], acc[m][n], 0, 0, 0);
                    acc[m][n] = __builtin_amdgcn_mfma_f32_16x16x32_bf16(ah[m], bl[n], acc[m][n], 0, 0, 0);
                }
        }
        __syncthreads();
    }
    #pragma unroll
    for (int m = 0; m < 4; ++m)
        #pragma unroll
        for (int n = 0; n < 2; ++n)
            #pragma unroll
            for (int j = 0; j < 4; ++j) {
                int row = m0 + wr * 64 + m * 16 + lg * 4 + j;
                int col = n0 + wc * 32 + n * 16 + lr;
                float o = acc[m][n][j];
                if (EPI == 1) {
                    ((float*)Cv + (size_t)z * czs)[(size_t)row * ldc + col] = sigf(o);
                } else if (EPI == 2) {
                    ((unsigned short*)Cv + (size_t)z * czs)[(size_t)row * ldc + col] = bfr(o);
                } else {
                    ((float*)Cv + (size_t)z * czs)[(size_t)row * ldc + col] = o;
                }
            }
}

// ---------------- GCN layer1 aggregate: h = relu(Agg(xwb)+b1) -> bf16, 128 thr ------
__global__ void k_gcn_a1(const unsigned int* __restrict__ xwb, const float* __restrict__ dinv,
                         const int* __restrict__ rp, const int* __restrict__ cs,
                         const float* __restrict__ b1, unsigned int* __restrict__ hb) {
    int d = blockIdx.x;
    int t = threadIdx.x;                         // 128 uint cols (256 fp cols)
    float dd = dinv[d];
    float2 sv = unpk(xwb[(size_t)d * 128 + t]);
    float a0 = dd * sv.x, a1 = dd * sv.y;
    int e0 = rp[d], e1 = rp[d + 1];
    int j = e0;
    for (; j + 4 <= e1; j += 4) {
        int s0 = cs[j], s1 = cs[j + 1], s2 = cs[j + 2], s3 = cs[j + 3];
        float w0 = dinv[s0], w1 = dinv[s1], w2 = dinv[s2], w3 = dinv[s3];
        float2 v0 = unpk(xwb[(size_t)s0 * 128 + t]);
        float2 v1 = unpk(xwb[(size_t)s1 * 128 + t]);
        float2 v2 = unpk(xwb[(size_t)s2 * 128 + t]);
        float2 v3 = unpk(xwb[(size_t)s3 * 128 + t]);
        a0 += w0 * v0.x + w1 * v1.x + w2 * v2.x + w3 * v3.x;
        a1 += w0 * v0.y + w1 * v1.y + w2 * v2.y + w3 * v3.y;
    }
    for (; j < e1; ++j) {
        int s = cs[j];
        float w = dinv[s];
        float2 v = unpk(xwb[(size_t)s * 128 + t]);
        a0 += w * v.x;
        a1 += w * v.y;
    }
    float o0 = fmaxf(dd * a0 + b1[2 * t], 0.f);
    float o1 = fmaxf(dd * a1 + b1[2 * t + 1], 0.f);
    hb[(size_t)d * 128 + t] = pack2(o0, o1);
}

// ---------------- GCN second aggregate: hA = Agg(h) -> split bf16, 128 thr ----------
__global__ void k_gcn_a2(const unsigned int* __restrict__ hb, const float* __restrict__ dinv,
                         const int* __restrict__ rp, const int* __restrict__ cs,
                         unsigned int* __restrict__ hA2u) {
    int d = blockIdx.x;
    int t = threadIdx.x;                         // 128 uint cols
    float dd = dinv[d];
    float2 sv = unpk(hb[(size_t)d * 128 + t]);
    float a0 = dd * sv.x, a1 = dd * sv.y;
    int e0 = rp[d], e1 = rp[d + 1];
    int j = e0;
    for (; j + 4 <= e1; j += 4) {
        int s0 = cs[j], s1 = cs[j + 1], s2 = cs[j + 2], s3 = cs[j + 3];
        float w0 = dinv[s0], w1 = dinv[s1], w2 = dinv[s2], w3 = dinv[s3];
        float2 v0 = unpk(hb[(size_t)s0 * 128 + t]);
        float2 v1 = unpk(hb[(size_t)s1 * 128 + t]);
        float2 v2 = unpk(hb[(size_t)s2 * 128 + t]);
        float2 v3 = unpk(hb[(size_t)s3 * 128 + t]);
        a0 += w0 * v0.x + w1 * v1.x + w2 * v2.x + w3 * v3.x;
        a1 += w0 * v0.y + w1 * v1.y + w2 * v2.y + w3 * v3.y;
    }
    for (; j < e1; ++j) {
        int s = cs[j];
        float w = dinv[s];
        float2 v = unpk(hb[(size_t)s * 128 + t]);
        a0 += w * v.x;
        a1 += w * v.y;
    }
    float o0 = dd * a0, o1 = dd * a1;
    int br = t >> 6, cu = t & 63;                // branch, uint col within branch
    unsigned short h0, l0, h1, l1;
    splitbf(o0, h0, l0);
    splitbf(o1, h1, l1);
    // hA2 row = 512 ushorts = 256 uints: [br*256 + hi(128) | lo(128)] ushorts
    hA2u[(size_t)d * 256 + br * 128 + cu] = (unsigned int)h0 | ((unsigned int)h1 << 16);
    hA2u[(size_t)d * 256 + br * 128 + 64 + cu] = (unsigned int)l0 | ((unsigned int)l1 << 16);
}

// ---------------- GAT layer1 logits from bf16 xwb (z = branch) ----------------
__global__ void k_gat_log1(const unsigned int* __restrict__ xwb, const float* __restrict__ a_s,
                           const float* __restrict__ a_d, float* __restrict__ as_n,
                           float* __restrict__ ad_n) {
    int br = blockIdx.z;
    int n = blockIdx.x;
    int hd = threadIdx.x >> 6, lane = threadIdx.x & 63;   // block 192
    const unsigned int* hp = xwb + (size_t)n * 384 + br * 192 + hd * 64;
    const float* av = a_s + br * 384 + hd * 128;
    const float* dv = a_d + br * 384 + hd * 128;
    float2 f = unpk(hp[lane]);
    float ss = f.x * av[2 * lane] + f.y * av[2 * lane + 1];
    float sd = f.x * dv[2 * lane] + f.y * dv[2 * lane + 1];
    #pragma unroll
    for (int off = 32; off; off >>= 1) {
        ss += __shfl_down(ss, off);
        sd += __shfl_down(sd, off);
    }
    if (lane == 0) {
        as_n[(size_t)br * NN * 3 + n * 3 + hd] = ss;
        ad_n[(size_t)br * NN * 3 + n * 3 + hd] = sd;
    }
}

// ---------------- GAT layer2 logits from bf16 h2gb (z = branch*2 + mtype) -----------
__global__ void k_gat_log2(const unsigned short* __restrict__ h2gb, const float* __restrict__ asmu,
                           const float* __restrict__ aslv, const float* __restrict__ admu,
                           const float* __restrict__ adlv, float* __restrict__ as_n,
                           float* __restrict__ ad_n) {
    int zz = blockIdx.z;
    int br = zz >> 1, mt = zz & 1;
    int n = blockIdx.x;
    int hd = threadIdx.x >> 6, lane = threadIdx.x & 63;   // block 192
    const unsigned short* hp = h2gb + (size_t)br * NN * 384 + (size_t)n * 384 + mt * 192 + hd * 64;
    const float* av = (mt ? aslv : asmu) + br * 192 + hd * 64;
    const float* dv = (mt ? adlv : admu) + br * 192 + hd * 64;
    float hv = bf2f(hp[lane]);
    float ss = hv * av[lane];
    float sd = hv * dv[lane];
    #pragma unroll
    for (int off = 32; off; off >>= 1) {
        ss += __shfl_down(ss, off);
        sd += __shfl_down(sd, off);
    }
    if (lane == 0) {
        as_n[(size_t)zz * NN * 3 + n * 3 + hd] = ss;
        ad_n[(size_t)zz * NN * 3 + n * 3 + hd] = sd;
    }
}

// ---------------- GAT softmax weights (z batched, wave per head) ----------------
__global__ void k_gat_attn(const float* __restrict__ as_n, const float* __restrict__ ad_n,
                           const int* __restrict__ rp, const int* __restrict__ cs,
                           float* __restrict__ w_csr, float* __restrict__ w_self, int E3) {
    int zz = blockIdx.z;
    as_n += (size_t)zz * NN * 3;
    ad_n += (size_t)zz * NN * 3;
    w_csr += (size_t)zz * E3;
    w_self += (size_t)zz * NN * 3;
    int d = blockIdx.x;
    int hd = threadIdx.x >> 6, lane = threadIdx.x & 63;   // block 192
    int e0 = rp[d], e1 = rp[d + 1];
    float add = ad_n[d * 3 + hd];
    float eself = lrelu(as_n[d * 3 + hd] + add);
    float mx = eself;
    for (int j = e0 + lane; j < e1; j += 64) {
        float e = lrelu(as_n[cs[j] * 3 + hd] + add);
        w_csr[(size_t)j * 3 + hd] = e;
        mx = fmaxf(mx, e);
    }
    #pragma unroll
    for (int off = 32; off; off >>= 1) mx = fmaxf(mx, __shfl_xor(mx, off));
    float sm = (lane == 0) ? __expf(eself - mx) : 0.f;
    for (int j = e0 + lane; j < e1; j += 64)
        sm += __expf(w_csr[(size_t)j * 3 + hd] - mx);
    #pragma unroll
    for (int off = 32; off; off >>= 1) sm += __shfl_xor(sm, off);
    float inv = 1.f / sm;
    if (lane == 0) w_self[d * 3 + hd] = __expf(eself - mx) * inv;
    for (int j = e0 + lane; j < e1; j += 64)
        w_csr[(size_t)j * 3 + hd] = __expf(w_csr[(size_t)j * 3 + hd] - mx) * inv;
}

// ---------------- GAT layer1 aggregate, both branches (384 thr, 2 fp cols each) -----
__global__ void k_gat_agg1(const unsigned int* __restrict__ xwb, const float* __restrict__ w_csr,
                           const float* __restrict__ w_self, const int* __restrict__ rp,
                           const int* __restrict__ cs, const float* __restrict__ b1,
                           unsigned int* __restrict__ h1su, int E3) {
    int d = blockIdx.x;
    int t = threadIdx.x;                          // 384 uint cols (768 fp)
    int br = t >= 192 ? 1 : 0;
    int cu = t - br * 192;                        // uint col within branch
    int hd = cu >> 6;
    const float* wc = w_csr + (size_t)br * E3;
    float ws = w_self[(size_t)br * NN * 3 + d * 3 + hd];
    float2 sv = unpk(xwb[(size_t)d * 384 + t]);
    float a0 = ws * sv.x, a1 = ws * sv.y;
    int e0 = rp[d], e1 = rp[d + 1];
    int j = e0;
    for (; j + 4 <= e1; j += 4) {
        int s0 = cs[j], s1 = cs[j + 1], s2 = cs[j + 2], s3 = cs[j + 3];
        float w0 = wc[(size_t)(j + 0) * 3 + hd];
        float w1 = wc[(size_t)(j + 1) * 3 + hd];
        float w2 = wc[(size_t)(j + 2) * 3 + hd];
        float w3 = wc[(size_t)(j + 3) * 3 + hd];
        float2 v0 = unpk(xwb[(size_t)s0 * 384 + t]);
        float2 v1 = unpk(xwb[(size_t)s1 * 384 + t]);
        float2 v2 = unpk(xwb[(size_t)s2 * 384 + t]);
        float2 v3 = unpk(xwb[(size_t)s3 * 384 + t]);
        a0 += w0 * v0.x + w1 * v1.x + w2 * v2.x + w3 * v3.x;
        a1 += w0 * v0.y + w1 * v1.y + w2 * v2.y + w3 * v3.y;
    }
    for (; j < e1; ++j) {
        int s = cs[j];
        float w = wc[(size_t)j * 3 + hd];
        float2 v = unpk(xwb[(size_t)s * 384 + t]);
        a0 += w * v.x;
        a1 += w * v.y;
    }
    float o0 = fmaxf(a0 + b1[br * 384 + 2 * cu], 0.f);
    float o1 = fmaxf(a1 + b1[br * 384 + 2 * cu + 1], 0.f);
    unsigned short h0, l0, h1, l1;
    splitbf(o0, h0, l0);
    splitbf(o1, h1, l1);
    // h1s row = 1536 ushorts = 768 uints: [br*768 + hi(384) | lo(384)] ushorts
    h1su[(size_t)d * 768 + br * 384 + cu] = (unsigned int)h0 | ((unsigned int)h1 << 16);
    h1su[(size_t)d * 768 + br * 384 + 192 + cu] = (unsigned int)l0 | ((unsigned int)l1 << 16);
}

// ---------------- GAT layer2 aggregate, mu+lv (z = branch, 192 thr) ----------------
__global__ void k_gat_agg2(const unsigned int* __restrict__ h2gu, const float* __restrict__ w_csr,
                           const float* __restrict__ w_self, const int* __restrict__ rp,
                           const int* __restrict__ cs, const float* __restrict__ bmu,
                           const float* __restrict__ blv, float* __restrict__ mt_gat, int E3) {
    int br = blockIdx.z;
    int d = blockIdx.x;
    int t = threadIdx.x;                          // 192 uint cols (384 fp: mu192|lv192)
    int mt = t >= 96 ? 1 : 0;
    int cu = t - mt * 96;
    int hd = cu >> 5;                             // 32 uints per head
    const unsigned int* hp = h2gu + (size_t)br * NN * 192;
    const float* wc = w_csr + (size_t)(br * 2 + mt) * E3;
    float ws = w_self[(size_t)(br * 2 + mt) * NN * 3 + d * 3 + hd];
    float2 sv = unpk(hp[(size_t)d * 192 + t]);
    float a0 = ws * sv.x, a1 = ws * sv.y;
    int e0 = rp[d], e1 = rp[d + 1];
    int j = e0;
    for (; j + 4 <= e1; j += 4) {
        int s0 = cs[j], s1 = cs[j + 1], s2 = cs[j + 2], s3 = cs[j + 3];
        float w0 = wc[(size_t)(j + 0) * 3 + hd];
        float w1 = wc[(size_t)(j + 1) * 3 + hd];
        float w2 = wc[(size_t)(j + 2) * 3 + hd];
        float w3 = wc[(size_t)(j + 3) * 3 + hd];
        float2 v0 = unpk(hp[(size_t)s0 * 192 + t]);
        float2 v1 = unpk(hp[(size_t)s1 * 192 + t]);
        float2 v2 = unpk(hp[(size_t)s2 * 192 + t]);
        float2 v3 = unpk(hp[(size_t)s3 * 192 + t]);
        a0 += w0 * v0.x + w1 * v1.x + w2 * v2.x + w3 * v3.x;
        a1 += w0 * v0.y + w1 * v1.y + w2 * v2.y + w3 * v3.y;
    }
    for (; j < e1; ++j) {
        int s = cs[j];
        float w = wc[(size_t)j * 3 + hd];
        float2 v = unpk(hp[(size_t)s * 192 + t]);
        a0 += w * v.x;
        a1 += w * v.y;
    }
    __shared__ float red[384];                    // fp-col indexed
    red[2 * t] = a0;
    red[2 * t + 1] = a1;
    __syncthreads();
    if (t < 128) {
        int mt2 = t >> 6, dd = t & 63;
        float tot = red[mt2 * 192 + dd] + red[mt2 * 192 + 64 + dd] + red[mt2 * 192 + 128 + dd];
        const float* bias = mt2 ? blv : bmu;
        float o = tot * (1.f / 3.f) + bias[br * 64 + dd];
        mt_gat[((size_t)(br * 2 + mt2) * NN + d) * 64 + dd] = o;
    }
}

// ---------------- finalize: bias, z, 4-way max, outputs + split z2 ----------------
__global__ void k_finalize(const float* __restrict__ muv_gcn, const float* __restrict__ gcn_bmu,
                           const float* __restrict__ gcn_blv, const float* __restrict__ mt_gat,
                           const float* __restrict__ eps_gcn, const float* __restrict__ eps_gat,
                           float* __restrict__ mu_o, float* __restrict__ lv_o,
                           unsigned short* __restrict__ z2) {
    int i = blockIdx.x * 256 + threadIdx.x;       // NN*64
    int d = i >> 6, c = i & 63;
    const size_t NN64 = (size_t)NN * 64;
    float mu, lv, zm;
    {
        float m = muv_gcn[(size_t)d * 128 + c] + gcn_bmu[c];
        float l = muv_gcn[(size_t)d * 128 + 64 + c] + gcn_blv[c];
        float z = m + eps_gcn[i] * __expf(l);
        mu = m; lv = l; zm = z;
    }
    {
        float m = muv_gcn[NN64 * 2 + (size_t)d * 128 + c] + gcn_bmu[64 + c];
        float l = muv_gcn[NN64 * 2 + (size_t)d * 128 + 64 + c] + gcn_blv[64 + c];
        float z = m + eps_gcn[NN64 + i] * __expf(l);
        mu = fmaxf(mu, m); lv = fmaxf(lv, l); zm = fmaxf(zm, z);
    }
    #pragma unroll
    for (int br = 0; br < 2; ++br) {
        float m = mt_gat[(size_t)(br * 2 + 0) * NN64 + i];
        float l = mt_gat[(size_t)(br * 2 + 1) * NN64 + i];
        float z = m + eps_gat[(size_t)br * NN64 + i] * __expf(l);
        mu = fmaxf(mu, m); lv = fmaxf(lv, l); zm = fmaxf(zm, z);
    }
    mu_o[i] = mu;
    lv_o[i] = lv;
    unsigned short hh, ll;
    splitbf(zm, hh, ll);
    z2[(size_t)d * 128 + c] = hh;
    z2[(size_t)d * 128 + 64 + c] = ll;
}

extern "C" void kernel_launch(void* const* d_in, const int* in_sizes, int n_in,
                              void* d_out, int out_size, void* d_ws, size_t ws_size,
                              hipStream_t stream) {
    const float* x  = (const float*)d_in[0];
    const int*   ei = (const int*)d_in[1];
    const int E = in_sizes[1] / 2;
    const int E3 = E * 3;
    const int* src = ei;
    const int* dst = ei + E;

    const float* gcn_W1  = (const float*)d_in[2];
    const float* gcn_b1  = (const float*)d_in[3];
    const float* gcn_Wmu = (const float*)d_in[4];
    const float* gcn_bmu = (const float*)d_in[5];
    const float* gcn_Wlv = (const float*)d_in[6];
    const float* gcn_blv = (const float*)d_in[7];
    const float* gat_W1  = (const float*)d_in[8];
    const float* gat_as1 = (const float*)d_in[9];
    const float* gat_ad1 = (const float*)d_in[10];
    const float* gat_b1  = (const float*)d_in[11];
    const float* gat_Wmu = (const float*)d_in[12];
    const float* gat_asmu= (const float*)d_in[13];
    const float* gat_admu= (const float*)d_in[14];
    const float* gat_bmu = (const float*)d_in[15];
    const float* gat_Wlv = (const float*)d_in[16];
    const float* gat_aslv= (const float*)d_in[17];
    const float* gat_adlv= (const float*)d_in[18];
    const float* gat_blv = (const float*)d_in[19];
    const float* eps_gcn = (const float*)d_in[20];
    const float* eps_gat = (const float*)d_in[21];

    // ---- workspace carve ----
    char* p = (char*)d_ws;
    auto alloc = [&](size_t bytes) {
        void* r = (void*)p;
        p += (bytes + 255) & ~(size_t)255;
        return r;
    };
    int*   cnt     = (int*)alloc((size_t)NN * 4);
    int*   cursor  = (int*)alloc((size_t)NN * 4);
    int*   row_ptr = (int*)alloc((size_t)(NN + 1) * 4);
    int*   csr_src = (int*)alloc((size_t)E * 4);
    float* dinv    = (float*)alloc((size_t)NN * 4);
    float* as_n1   = (float*)alloc((size_t)2 * NN * 3 * 4);
    float* ad_n1   = (float*)alloc((size_t)2 * NN * 3 * 4);
    float* wself1  = (float*)alloc((size_t)2 * NN * 3 * 4);
    float* wcsr1   = (float*)alloc((size_t)2 * E3 * 4);
    float* as_n2   = (float*)alloc((size_t)4 * NN * 3 * 4);
    float* ad_n2   = (float*)alloc((size_t)4 * NN * 3 * 4);
    float* wself2  = (float*)alloc((size_t)4 * NN * 3 * 4);
    float* wcsr2   = (float*)alloc((size_t)4 * E3 * 4);
    unsigned short* x2       = (unsigned short*)alloc((size_t)NN * 1024 * 2);
    unsigned short* wt_gcn1  = (unsigned short*)alloc((size_t)256 * 1024 * 2);
    unsigned short* wt_gcnmuv= (unsigned short*)alloc((size_t)2 * 128 * 256 * 2);
    unsigned short* wt_gat1  = (unsigned short*)alloc((size_t)768 * 1024 * 2);
    unsigned short* wt_gatmuv= (unsigned short*)alloc((size_t)2 * 384 * 768 * 2);
    unsigned int* xwb  = (unsigned int*)alloc((size_t)NN * 384 * 4);   // bf16x2; GCN uses ld 128
    unsigned int* hb   = (unsigned int*)alloc((size_t)NN * 128 * 4);   // GCN h bf16x2
    unsigned int* hA2u = (unsigned int*)alloc((size_t)NN * 256 * 4);   // split bf16
    float* muv_gcn = (float*)alloc((size_t)2 * NN * 128 * 4);
    unsigned int* h1su = (unsigned int*)alloc((size_t)NN * 768 * 4);   // split bf16
    unsigned short* h2gb = (unsigned short*)alloc((size_t)2 * NN * 384 * 2);  // bf16
    float* mt_gat  = (float*)alloc((size_t)4 * NN * 64 * 4);
    unsigned short* z2 = (unsigned short*)alloc((size_t)NN * 128 * 2);

    float* adj  = (float*)d_out;
    float* mu_o = adj + (size_t)NN * NN;
    float* lv_o = mu_o + (size_t)NN * 64;

    // ---- CSR build ----
    k_zero<<<(2 * NN + 255) / 256, 256, 0, stream>>>(cnt, 2 * NN);
    k_count<<<(E + 255) / 256, 256, 0, stream>>>(dst, cnt, E);
    k_dinv<<<(NN + 255) / 256, 256, 0, stream>>>(cnt, dinv);
    k_scan<<<1, 1024, 0, stream>>>(cnt, row_ptr);
    k_fill<<<(E + 255) / 256, 256, 0, stream>>>(src, dst, row_ptr, cursor, csr_src, E);

    // ---- precision prep ----
    k_split_x<<<NN * 512 / 4 / 256, 256, 0, stream>>>(x, x2);
    k_wsplitT<<<dim3(16, 4, 2), 256, 0, stream>>>(gcn_W1, wt_gcn1, 512, 128, 0, 0, 128);
    k_wsplitT<<<dim3(4, 2, 2), 256, 0, stream>>>(gcn_Wmu, wt_gcnmuv, 128, 64,
                                                 (size_t)128 * 256, 0, 0);
    k_wsplitT<<<dim3(4, 2, 2), 256, 0, stream>>>(gcn_Wlv, wt_gcnmuv, 128, 64,
                                                 (size_t)128 * 256, 64, 0);
    k_wsplitT<<<dim3(16, 12, 2), 256, 0, stream>>>(gat_W1, wt_gat1, 512, 384, 0, 0, 384);
    k_wsplitT<<<dim3(12, 6, 2), 256, 0, stream>>>(gat_Wmu, wt_gatmuv, 384, 192,
                                                  (size_t)384 * 768, 0, 0);
    k_wsplitT<<<dim3(12, 6, 2), 256, 0, stream>>>(gat_Wlv, wt_gatmuv, 384, 192,
                                                  (size_t)384 * 768, 192, 0);

    // ---- GCN (both branches batched) ----
    // g1: xwb[:, :256] = bf16(x2 @ wt_gcn1)  (K=512, N=256), ldc=256 ushorts
    k_gemm2<2><<<dim3(64, 4, 1), 256, 0, stream>>>(x2, 0, 1024, wt_gcn1, 0, 1024,
                                                   xwb, 0, 256, 512);
    k_gcn_a1<<<NN, 128, 0, stream>>>(xwb, dinv, row_ptr, csr_src, gcn_b1, hb);
    k_gcn_a2<<<NN, 128, 0, stream>>>(hb, dinv, row_ptr, csr_src, hA2u);
    // g2: muv[z] = hA2[z] @ wt_gcnmuv[z]  (K=128, N=128), z=branch, fp32 out
    k_gemm2<0><<<dim3(64, 2, 2), 256, 0, stream>>>((const unsigned short*)hA2u, 256, 512,
                                                   wt_gcnmuv, (size_t)128 * 256, 256,
                                                   muv_gcn, (size_t)NN * 128, 128, 128);

    // ---- GAT (both branches batched) ----
    // G1: xwb = bf16(x2 @ wt_gat1)  (K=512, N=768), ldc=768 ushorts
    k_gemm2<2><<<dim3(64, 12, 1), 256, 0, stream>>>(x2, 0, 1024, wt_gat1, 0, 1024,
                                                    xwb, 0, 768, 512);
    k_gat_log1<<<dim3(NN, 1, 2), 192, 0, stream>>>(xwb, gat_as1, gat_ad1, as_n1, ad_n1);
    k_gat_attn<<<dim3(NN, 1, 2), 192, 0, stream>>>(as_n1, ad_n1, row_ptr, csr_src,
                                                   wcsr1, wself1, E3);
    k_gat_agg1<<<NN, 384, 0, stream>>>(xwb, wcsr1, wself1, row_ptr, csr_src, gat_b1,
                                       h1su, E3);
    // G2: h2gb[z] = bf16(h1s[z] @ wt_gatmuv[z])  (K=384, N=384), z=branch
    k_gemm2<2><<<dim3(64, 6, 2), 256, 0, stream>>>((const unsigned short*)h1su, 768, 1536,
                                                   wt_gatmuv, (size_t)384 * 768, 768,
                                                   h2gb, (size_t)NN * 384, 384, 384);
    k_gat_log2<<<dim3(NN, 1, 4), 192, 0, stream>>>(h2gb, gat_asmu, gat_aslv, gat_admu,
                                                   gat_adlv, as_n2, ad_n2);
    k_gat_attn<<<dim3(NN, 1, 4), 192, 0, stream>>>(as_n2, ad_n2, row_ptr, csr_src,
                                                   wcsr2, wself2, E3);
    k_gat_agg2<<<dim3(NN, 1, 2), 192, 0, stream>>>((const unsigned int*)h2gb, wcsr2, wself2,
                                                   row_ptr, csr_src, gat_bmu, gat_blv,
                                                   mt_gat, E3);

    // ---- finalize + adjacency ----
    k_finalize<<<NN * 64 / 256, 256, 0, stream>>>(muv_gcn, gcn_bmu, gcn_blv, mt_gat,
                                                  eps_gcn, eps_gat, mu_o, lv_o, z2);
    k_gemm2<1><<<dim3(64, 128, 1), 256, 0, stream>>>(z2, 0, 128, z2, 0, 128,
                                                     adj, 0, NN, 64);
}

// Round 6
// 364.841 us; speedup vs baseline: 3.1174x; 1.0695x over previous
//
#include <hip/hip_runtime.h>
#include <hip/hip_bf16.h>
#include <math.h>
#include <stddef.h>

#define NN 8192
#define NEG_SLOPE 0.2f

typedef _Float16 h8 __attribute__((ext_vector_type(8)));
typedef __attribute__((ext_vector_type(4))) float f32x4;

__device__ __forceinline__ float lrelu(float x) { return x > 0.f ? x : NEG_SLOPE * x; }
__device__ __forceinline__ float sigf(float x) { return 1.f / (1.f + __expf(-x)); }

__device__ __forceinline__ unsigned short f16b(float x) {
    _Float16 h = (_Float16)x;
    unsigned short u;
    __builtin_memcpy(&u, &h, 2);
    return u;
}
__device__ __forceinline__ float f16f(unsigned short u) {
    _Float16 h;
    __builtin_memcpy(&h, &u, 2);
    return (float)h;
}
__device__ __forceinline__ void splith(float x, unsigned short& hu, unsigned short& lu) {
    _Float16 h = (_Float16)x;
    float hf = (float)h;
    _Float16 l = (_Float16)(x - hf);
    __builtin_memcpy(&hu, &h, 2);
    __builtin_memcpy(&lu, &l, 2);
}
__device__ __forceinline__ float2 unpkh(unsigned int v) {
    float2 r;
    r.x = f16f((unsigned short)(v & 0xffffu));
    r.y = f16f((unsigned short)(v >> 16));
    return r;
}
__device__ __forceinline__ unsigned int packh(float a, float b) {
    return (unsigned int)f16b(a) | ((unsigned int)f16b(b) << 16);
}

// async global->LDS, 16B per lane; lds base must be wave-uniform
__device__ __forceinline__ void gll16(const unsigned short* g, unsigned short* l) {
    __builtin_amdgcn_global_load_lds(
        (const __attribute__((address_space(1))) unsigned int*)g,
        (__attribute__((address_space(3))) unsigned int*)l, 16, 0, 0);
}

// ---------------- CSR build ----------------
__global__ void k_zero(int* __restrict__ p, int n) {
    int i = blockIdx.x * blockDim.x + threadIdx.x;
    if (i < n) p[i] = 0;
}
__global__ void k_count(const int* __restrict__ dst, int* __restrict__ cnt, int E) {
    int i = blockIdx.x * blockDim.x + threadIdx.x;
    if (i < E) atomicAdd(&cnt[dst[i]], 1);
}
__global__ void k_dinv(const int* __restrict__ cnt, float* __restrict__ dinv) {
    int i = blockIdx.x * blockDim.x + threadIdx.x;
    if (i < NN) dinv[i] = rsqrtf((float)(cnt[i] + 1));
}
__global__ void k_scan(const int* __restrict__ cnt, int* __restrict__ row_ptr) {
    __shared__ int part[1024];
    int t = threadIdx.x;
    int base = t * 8;
    int loc[8];
    int s = 0;
    #pragma unroll
    for (int j = 0; j < 8; ++j) { loc[j] = s; s += cnt[base + j]; }
    part[t] = s;
    __syncthreads();
    for (int off = 1; off < 1024; off <<= 1) {
        int v = (t >= off) ? part[t - off] : 0;
        __syncthreads();
        part[t] += v;
        __syncthreads();
    }
    int pre = (t == 0) ? 0 : part[t - 1];
    #pragma unroll
    for (int j = 0; j < 8; ++j) row_ptr[base + j] = pre + loc[j];
    if (t == 1023) row_ptr[NN] = part[1023];
}
__global__ void k_fill(const int* __restrict__ src, const int* __restrict__ dst,
                       const int* __restrict__ row_ptr, int* __restrict__ cursor,
                       int* __restrict__ csr_src, int E) {
    int i = blockIdx.x * blockDim.x + threadIdx.x;
    if (i < E) {
        int d = dst[i];
        csr_src[row_ptr[d] + atomicAdd(&cursor[d], 1)] = src[i];
    }
}

// ---------------- x fp32 -> fp16 ----------------
__global__ void k_cvt_x(const float* __restrict__ x, unsigned short* __restrict__ xh) {
    int i = blockIdx.x * 256 + threadIdx.x;     // over NN*512/4
    int m = i >> 7, k4 = (i & 127) * 4;
    float4 v = *(const float4*)(x + (size_t)m * 512 + k4);
    ushort4 o;
    o.x = f16b(v.x); o.y = f16b(v.y); o.z = f16b(v.z); o.w = f16b(v.w);
    *(ushort4*)&xh[(size_t)m * 512 + k4] = o;
}

// W[z] [K,N] fp32 -> Wt fp16 rows (noff + z*noff_z + n) of length K
__global__ void k_wT(const float* __restrict__ W, unsigned short* __restrict__ Wt,
                     int K, int N, size_t wt_z_stride, int noff, int noff_z) {
    int b = blockIdx.z;
    W += (size_t)b * K * N;
    Wt += (size_t)b * wt_z_stride;
    int rowbase = noff + b * noff_z;
    int k0 = blockIdx.x * 32, n0 = blockIdx.y * 32;
    __shared__ float tl[32][33];
    int tid = threadIdx.x;
    int r = tid >> 5, cc = tid & 31;
    #pragma unroll
    for (int c = 0; c < 4; ++c)
        tl[r + c * 8][cc] = W[(size_t)(k0 + r + c * 8) * N + n0 + cc];
    __syncthreads();
    #pragma unroll
    for (int c = 0; c < 4; ++c) {
        int n = r + c * 8, k = cc;
        Wt[(size_t)(rowbase + n0 + n) * K + k0 + k] = f16b(tl[k][n]);
    }
}

// ---------------- fp16 MFMA GEMM, global_load_lds staging ----------------
// A2 [M rows, lda] fp16; TERMS=3: hi at col k, lo at col K+k. B2 same with ldb.
// BM=128, BN=64, BK=64, 256 threads (4 waves), per-wave 64x32 out.
template <int ROWS>
__device__ __forceinline__ void stage(const unsigned short* __restrict__ gbase, int lda,
                                      unsigned short* lds, int wid, int lane) {
    #pragma unroll
    for (int c = 0; c < ROWS / 32; ++c) {
        int chunk = c * 4 + wid;                // 1KB chunks
        int row = chunk * 8 + (lane >> 3);
        int g = (lane & 7) ^ (row & 7);
        gll16(gbase + (size_t)row * lda + g * 8, lds + chunk * 512);
    }
}
__device__ __forceinline__ h8 fragrh(const unsigned short* lds, int row, int kg) {
    return *(const h8*)(lds + row * 64 + ((kg ^ (row & 7)) * 8));
}

template <int TERMS, int EPI>   // EPI: 0 fp32, 1 fp32+sigmoid, 2 fp16
__global__ __launch_bounds__(256) void k_gemm2(
    const unsigned short* __restrict__ A2, size_t azs, int lda,
    const unsigned short* __restrict__ B2, size_t bzs, int ldb,
    void* __restrict__ Cv, size_t czs, int ldc, int K) {
    __shared__ __align__(16) unsigned short sAh[128 * 64];
    __shared__ __align__(16) unsigned short sBh[64 * 64];
    __shared__ __align__(16) unsigned short sAl[(TERMS == 3) ? 128 * 64 : 8];
    __shared__ __align__(16) unsigned short sBl[(TERMS == 3) ? 64 * 64 : 8];
    const int tid = threadIdx.x;
    const int wid = tid >> 6, lane = tid & 63;
    const int wr = wid >> 1, wc = wid & 1;
    const int lr = lane & 15, lg = lane >> 4;
    const int m0 = blockIdx.x * 128, n0 = blockIdx.y * 64;
    const int z = blockIdx.z;
    A2 += (size_t)z * azs;
    B2 += (size_t)z * bzs;

    const f32x4 zero4 = {0.f, 0.f, 0.f, 0.f};
    f32x4 acc[4][2];
    #pragma unroll
    for (int m = 0; m < 4; ++m)
        #pragma unroll
        for (int n = 0; n < 2; ++n) acc[m][n] = zero4;

    for (int k0 = 0; k0 < K; k0 += 64) {
        stage<128>(A2 + (size_t)m0 * lda + k0, lda, sAh, wid, lane);
        stage<64> (B2 + (size_t)n0 * ldb + k0, ldb, sBh, wid, lane);
        if (TERMS == 3) {
            stage<128>(A2 + (size_t)m0 * lda + K + k0, lda, sAl, wid, lane);
            stage<64> (B2 + (size_t)n0 * ldb + K + k0, ldb, sBl, wid, lane);
        }
        __syncthreads();
        #pragma unroll
        for (int ks = 0; ks < 2; ++ks) {
            const int kg = ks * 4 + lg;
            h8 ah[4], al[4], bh[2], bl[2];
            #pragma unroll
            for (int m = 0; m < 4; ++m) {
                int row = wr * 64 + m * 16 + lr;
                ah[m] = fragrh(sAh, row, kg);
                if (TERMS == 3) al[m] = fragrh(sAl, row, kg);
            }
            #pragma unroll
            for (int n = 0; n < 2; ++n) {
                int row = wc * 32 + n * 16 + lr;
                bh[n] = fragrh(sBh, row, kg);
                if (TERMS == 3) bl[n] = fragrh(sBl, row, kg);
            }
            #pragma unroll
            for (int m = 0; m < 4; ++m)
                #pragma unroll
                for (int n = 0; n < 2; ++n) {
                    acc[m][n] = __builtin_amdgcn_mfma_f32_16x16x32_f16(ah[m], bh[n], acc[m][n], 0, 0, 0);
                    if (TERMS == 3) {
                        acc[m][n] = __builtin_amdgcn_mfma_f32_16x16x32_f16(al[m], bh[n], acc[m][n], 0, 0, 0);
                        acc[m][n] = __builtin_amdgcn_mfma_f32_16x16x32_f16(ah[m], bl[n], acc[m][n], 0, 0, 0);
                    }
                }
        }
        __syncthreads();
    }
    #pragma unroll
    for (int m = 0; m < 4; ++m)
        #pragma unroll
        for (int n = 0; n < 2; ++n)
            #pragma unroll
            for (int j = 0; j < 4; ++j) {
                int row = m0 + wr * 64 + m * 16 + lg * 4 + j;
                int col = n0 + wc * 32 + n * 16 + lr;
                float o = acc[m][n][j];
                if (EPI == 1) {
                    ((float*)Cv + (size_t)z * czs)[(size_t)row * ldc + col] = sigf(o);
                } else if (EPI == 2) {
                    ((unsigned short*)Cv + (size_t)z * czs)[(size_t)row * ldc + col] = f16b(o);
                } else {
                    ((float*)Cv + (size_t)z * czs)[(size_t)row * ldc + col] = o;
                }
            }
}

// ---------------- GCN layer1 aggregate: h = relu(Agg(xwh)+b1), 64 thr x uint2 --------
__global__ void k_gcn_a1(const uint2* __restrict__ xw2, const float* __restrict__ dinv,
                         const int* __restrict__ rp, const int* __restrict__ cs,
                         const float* __restrict__ b1, uint2* __restrict__ hb2) {
    int d = blockIdx.x;
    int t = threadIdx.x;                         // 64 uint2 cols (256 fp)
    float dd = dinv[d];
    uint2 sv = xw2[(size_t)d * 64 + t];
    float2 s0 = unpkh(sv.x), s1 = unpkh(sv.y);
    float a0 = dd * s0.x, a1 = dd * s0.y, a2 = dd * s1.x, a3 = dd * s1.y;
    int e0 = rp[d], e1 = rp[d + 1];
    int j = e0;
    for (; j + 4 <= e1; j += 4) {
        int i0 = cs[j], i1 = cs[j + 1], i2 = cs[j + 2], i3 = cs[j + 3];
        float w0 = dinv[i0], w1 = dinv[i1], w2 = dinv[i2], w3 = dinv[i3];
        uint2 v0 = xw2[(size_t)i0 * 64 + t];
        uint2 v1 = xw2[(size_t)i1 * 64 + t];
        uint2 v2 = xw2[(size_t)i2 * 64 + t];
        uint2 v3 = xw2[(size_t)i3 * 64 + t];
        float2 p;
        p = unpkh(v0.x); a0 += w0 * p.x; a1 += w0 * p.y;
        p = unpkh(v0.y); a2 += w0 * p.x; a3 += w0 * p.y;
        p = unpkh(v1.x); a0 += w1 * p.x; a1 += w1 * p.y;
        p = unpkh(v1.y); a2 += w1 * p.x; a3 += w1 * p.y;
        p = unpkh(v2.x); a0 += w2 * p.x; a1 += w2 * p.y;
        p = unpkh(v2.y); a2 += w2 * p.x; a3 += w2 * p.y;
        p = unpkh(v3.x); a0 += w3 * p.x; a1 += w3 * p.y;
        p = unpkh(v3.y); a2 += w3 * p.x; a3 += w3 * p.y;
    }
    for (; j < e1; ++j) {
        int s = cs[j];
        float w = dinv[s];
        uint2 v = xw2[(size_t)s * 64 + t];
        float2 p;
        p = unpkh(v.x); a0 += w * p.x; a1 += w * p.y;
        p = unpkh(v.y); a2 += w * p.x; a3 += w * p.y;
    }
    int c = 4 * t;
    float o0 = fmaxf(dd * a0 + b1[c], 0.f);
    float o1 = fmaxf(dd * a1 + b1[c + 1], 0.f);
    float o2 = fmaxf(dd * a2 + b1[c + 2], 0.f);
    float o3 = fmaxf(dd * a3 + b1[c + 3], 0.f);
    uint2 o;
    o.x = packh(o0, o1);
    o.y = packh(o2, o3);
    hb2[(size_t)d * 64 + t] = o;
}

// ---------------- GCN second aggregate: hA = Agg(h) fp16, 64 thr x uint2 ------------
__global__ void k_gcn_a2(const uint2* __restrict__ hb2, const float* __restrict__ dinv,
                         const int* __restrict__ rp, const int* __restrict__ cs,
                         uint2* __restrict__ hA2) {
    int d = blockIdx.x;
    int t = threadIdx.x;                         // 64 uint2 cols
    float dd = dinv[d];
    uint2 sv = hb2[(size_t)d * 64 + t];
    float2 s0 = unpkh(sv.x), s1 = unpkh(sv.y);
    float a0 = dd * s0.x, a1 = dd * s0.y, a2 = dd * s1.x, a3 = dd * s1.y;
    int e0 = rp[d], e1 = rp[d + 1];
    int j = e0;
    for (; j + 4 <= e1; j += 4) {
        int i0 = cs[j], i1 = cs[j + 1], i2 = cs[j + 2], i3 = cs[j + 3];
        float w0 = dinv[i0], w1 = dinv[i1], w2 = dinv[i2], w3 = dinv[i3];
        uint2 v0 = hb2[(size_t)i0 * 64 + t];
        uint2 v1 = hb2[(size_t)i1 * 64 + t];
        uint2 v2 = hb2[(size_t)i2 * 64 + t];
        uint2 v3 = hb2[(size_t)i3 * 64 + t];
        float2 p;
        p = unpkh(v0.x); a0 += w0 * p.x; a1 += w0 * p.y;
        p = unpkh(v0.y); a2 += w0 * p.x; a3 += w0 * p.y;
        p = unpkh(v1.x); a0 += w1 * p.x; a1 += w1 * p.y;
        p = unpkh(v1.y); a2 += w1 * p.x; a3 += w1 * p.y;
        p = unpkh(v2.x); a0 += w2 * p.x; a1 += w2 * p.y;
        p = unpkh(v2.y); a2 += w2 * p.x; a3 += w2 * p.y;
        p = unpkh(v3.x); a0 += w3 * p.x; a1 += w3 * p.y;
        p = unpkh(v3.y); a2 += w3 * p.x; a3 += w3 * p.y;
    }
    for (; j < e1; ++j) {
        int s = cs[j];
        float w = dinv[s];
        uint2 v = hb2[(size_t)s * 64 + t];
        float2 p;
        p = unpkh(v.x); a0 += w * p.x; a1 += w * p.y;
        p = unpkh(v.y); a2 += w * p.x; a3 += w * p.y;
    }
    uint2 o;
    o.x = packh(dd * a0, dd * a1);
    o.y = packh(dd * a2, dd * a3);
    hA2[(size_t)d * 64 + t] = o;
}

// ---------------- GAT layer1 logits (z = branch) ----------------
__global__ void k_gat_log1(const unsigned int* __restrict__ xwu, const float* __restrict__ a_s,
                           const float* __restrict__ a_d, float* __restrict__ as_n,
                           float* __restrict__ ad_n) {
    int br = blockIdx.z;
    int n = blockIdx.x;
    int hd = threadIdx.x >> 6, lane = threadIdx.x & 63;   // block 192
    const unsigned int* hp = xwu + (size_t)n * 384 + br * 192 + hd * 64;
    const float* av = a_s + br * 384 + hd * 128;
    const float* dv = a_d + br * 384 + hd * 128;
    float2 f = unpkh(hp[lane]);
    float ss = f.x * av[2 * lane] + f.y * av[2 * lane + 1];
    float sd = f.x * dv[2 * lane] + f.y * dv[2 * lane + 1];
    #pragma unroll
    for (int off = 32; off; off >>= 1) {
        ss += __shfl_down(ss, off);
        sd += __shfl_down(sd, off);
    }
    if (lane == 0) {
        as_n[(size_t)br * NN * 3 + n * 3 + hd] = ss;
        ad_n[(size_t)br * NN * 3 + n * 3 + hd] = sd;
    }
}

// ---------------- GAT layer2 logits (z = branch*2 + mtype) ----------------
__global__ void k_gat_log2(const unsigned short* __restrict__ h2gb, const float* __restrict__ asmu,
                           const float* __restrict__ aslv, const float* __restrict__ admu,
                           const float* __restrict__ adlv, float* __restrict__ as_n,
                           float* __restrict__ ad_n) {
    int zz = blockIdx.z;
    int br = zz >> 1, mt = zz & 1;
    int n = blockIdx.x;
    int hd = threadIdx.x >> 6, lane = threadIdx.x & 63;   // block 192
    const unsigned short* hp = h2gb + (size_t)br * NN * 384 + (size_t)n * 384 + mt * 192 + hd * 64;
    const float* av = (mt ? aslv : asmu) + br * 192 + hd * 64;
    const float* dv = (mt ? adlv : admu) + br * 192 + hd * 64;
    float hv = f16f(hp[lane]);
    float ss = hv * av[lane];
    float sd = hv * dv[lane];
    #pragma unroll
    for (int off = 32; off; off >>= 1) {
        ss += __shfl_down(ss, off);
        sd += __shfl_down(sd, off);
    }
    if (lane == 0) {
        as_n[(size_t)zz * NN * 3 + n * 3 + hd] = ss;
        ad_n[(size_t)zz * NN * 3 + n * 3 + hd] = sd;
    }
}

// ---------------- GAT softmax weights (z batched, wave per head) ----------------
__global__ void k_gat_attn(const float* __restrict__ as_n, const float* __restrict__ ad_n,
                           const int* __restrict__ rp, const int* __restrict__ cs,
                           float* __restrict__ w_csr, float* __restrict__ w_self, int E3) {
    int zz = blockIdx.z;
    as_n += (size_t)zz * NN * 3;
    ad_n += (size_t)zz * NN * 3;
    w_csr += (size_t)zz * E3;
    w_self += (size_t)zz * NN * 3;
    int d = blockIdx.x;
    int hd = threadIdx.x >> 6, lane = threadIdx.x & 63;   // block 192
    int e0 = rp[d], e1 = rp[d + 1];
    float add = ad_n[d * 3 + hd];
    float eself = lrelu(as_n[d * 3 + hd] + add);
    float mx = eself;
    for (int j = e0 + lane; j < e1; j += 64) {
        float e = lrelu(as_n[cs[j] * 3 + hd] + add);
        w_csr[(size_t)j * 3 + hd] = e;
        mx = fmaxf(mx, e);
    }
    #pragma unroll
    for (int off = 32; off; off >>= 1) mx = fmaxf(mx, __shfl_xor(mx, off));
    float sm = (lane == 0) ? __expf(eself - mx) : 0.f;
    for (int j = e0 + lane; j < e1; j += 64)
        sm += __expf(w_csr[(size_t)j * 3 + hd] - mx);
    #pragma unroll
    for (int off = 32; off; off >>= 1) sm += __shfl_xor(sm, off);
    float inv = 1.f / sm;
    if (lane == 0) w_self[d * 3 + hd] = __expf(eself - mx) * inv;
    for (int j = e0 + lane; j < e1; j += 64)
        w_csr[(size_t)j * 3 + hd] = __expf(w_csr[(size_t)j * 3 + hd] - mx) * inv;
}

// ---------------- GAT layer1 aggregate, both branches (192 thr x uint2) -------------
__global__ void k_gat_agg1(const uint2* __restrict__ xw2, const float* __restrict__ w_csr,
                           const float* __restrict__ w_self, const int* __restrict__ rp,
                           const int* __restrict__ cs, const float* __restrict__ b1,
                           uint2* __restrict__ h1s2, int E3) {
    int d = blockIdx.x;
    int t = threadIdx.x;                          // 192 uint2 cols (768 fp)
    int br = t >= 96 ? 1 : 0;
    int c = 4 * t - br * 384;                     // fp col within branch
    int hd = c >> 7;
    const float* wc = w_csr + (size_t)br * E3;
    float ws = w_self[(size_t)br * NN * 3 + d * 3 + hd];
    uint2 sv = xw2[(size_t)d * 192 + t];
    float2 s0 = unpkh(sv.x), s1 = unpkh(sv.y);
    float a0 = ws * s0.x, a1 = ws * s0.y, a2 = ws * s1.x, a3 = ws * s1.y;
    int e0 = rp[d], e1 = rp[d + 1];
    int j = e0;
    for (; j + 4 <= e1; j += 4) {
        int i0 = cs[j], i1 = cs[j + 1], i2 = cs[j + 2], i3 = cs[j + 3];
        float w0 = wc[(size_t)(j + 0) * 3 + hd];
        float w1 = wc[(size_t)(j + 1) * 3 + hd];
        float w2 = wc[(size_t)(j + 2) * 3 + hd];
        float w3 = wc[(size_t)(j + 3) * 3 + hd];
        uint2 v0 = xw2[(size_t)i0 * 192 + t];
        uint2 v1 = xw2[(size_t)i1 * 192 + t];
        uint2 v2 = xw2[(size_t)i2 * 192 + t];
        uint2 v3 = xw2[(size_t)i3 * 192 + t];
        float2 p;
        p = unpkh(v0.x); a0 += w0 * p.x; a1 += w0 * p.y;
        p = unpkh(v0.y); a2 += w0 * p.x; a3 += w0 * p.y;
        p = unpkh(v1.x); a0 += w1 * p.x; a1 += w1 * p.y;
        p = unpkh(v1.y); a2 += w1 * p.x; a3 += w1 * p.y;
        p = unpkh(v2.x); a0 += w2 * p.x; a1 += w2 * p.y;
        p = unpkh(v2.y); a2 += w2 * p.x; a3 += w2 * p.y;
        p = unpkh(v3.x); a0 += w3 * p.x; a1 += w3 * p.y;
        p = unpkh(v3.y); a2 += w3 * p.x; a3 += w3 * p.y;
    }
    for (; j < e1; ++j) {
        int s = cs[j];
        float w = wc[(size_t)j * 3 + hd];
        uint2 v = xw2[(size_t)s * 192 + t];
        float2 p;
        p = unpkh(v.x); a0 += w * p.x; a1 += w * p.y;
        p = unpkh(v.y); a2 += w * p.x; a3 += w * p.y;
    }
    int cg = 4 * t;                               // global fp col
    float o0 = fmaxf(a0 + b1[cg], 0.f);
    float o1 = fmaxf(a1 + b1[cg + 1], 0.f);
    float o2 = fmaxf(a2 + b1[cg + 2], 0.f);
    float o3 = fmaxf(a3 + b1[cg + 3], 0.f);
    uint2 o;
    o.x = packh(o0, o1);
    o.y = packh(o2, o3);
    h1s2[(size_t)d * 192 + t] = o;
}

// ---------------- GAT layer2 aggregate, both branches + mu/lv (192 thr) -------------
__global__ void k_gat_agg2(const uint2* __restrict__ h2g2, const float* __restrict__ w_csr,
                           const float* __restrict__ w_self, const int* __restrict__ rp,
                           const int* __restrict__ cs, const float* __restrict__ bmu,
                           const float* __restrict__ blv, float* __restrict__ mt_gat, int E3) {
    int d = blockIdx.x;
    int t = threadIdx.x;                          // 192: br(2) x 96 uint2 (384 fp each)
    int br = t >= 96 ? 1 : 0;
    int tb = t - br * 96;
    int mt = tb >= 48 ? 1 : 0;
    int c = 4 * tb - mt * 192;                    // fp col within (br,mt), 0..191
    int hd = c >> 6;
    const float* wc = w_csr + (size_t)(br * 2 + mt) * E3;
    float ws = w_self[(size_t)(br * 2 + mt) * NN * 3 + d * 3 + hd];
    const uint2* hp = h2g2 + (size_t)br * NN * 96;
    uint2 sv = hp[(size_t)d * 96 + tb];
    float2 s0 = unpkh(sv.x), s1 = unpkh(sv.y);
    float a0 = ws * s0.x, a1 = ws * s0.y, a2 = ws * s1.x, a3 = ws * s1.y;
    int e0 = rp[d], e1 = rp[d + 1];
    int j = e0;
    for (; j + 4 <= e1; j += 4) {
        int i0 = cs[j], i1 = cs[j + 1], i2 = cs[j + 2], i3 = cs[j + 3];
        float w0 = wc[(size_t)(j + 0) * 3 + hd];
        float w1 = wc[(size_t)(j + 1) * 3 + hd];
        float w2 = wc[(size_t)(j + 2) * 3 + hd];
        float w3 = wc[(size_t)(j + 3) * 3 + hd];
        uint2 v0 = hp[(size_t)i0 * 96 + tb];
        uint2 v1 = hp[(size_t)i1 * 96 + tb];
        uint2 v2 = hp[(size_t)i2 * 96 + tb];
        uint2 v3 = hp[(size_t)i3 * 96 + tb];
        float2 p;
        p = unpkh(v0.x); a0 += w0 * p.x; a1 += w0 * p.y;
        p = unpkh(v0.y); a2 += w0 * p.x; a3 += w0 * p.y;
        p = unpkh(v1.x); a0 += w1 * p.x; a1 += w1 * p.y;
        p = unpkh(v1.y); a2 += w1 * p.x; a3 += w1 * p.y;
        p = unpkh(v2.x); a0 += w2 * p.x; a1 += w2 * p.y;
        p = unpkh(v2.y); a2 += w2 * p.x; a3 += w2 * p.y;
        p = unpkh(v3.x); a0 += w3 * p.x; a1 += w3 * p.y;
        p = unpkh(v3.y); a2 += w3 * p.x; a3 += w3 * p.y;
    }
    for (; j < e1; ++j) {
        int s = cs[j];
        float w = wc[(size_t)j * 3 + hd];
        uint2 v = hp[(size_t)s * 96 + tb];
        float2 p;
        p = unpkh(v.x); a0 += w * p.x; a1 += w * p.y;
        p = unpkh(v.y); a2 += w * p.x; a3 += w * p.y;
    }
    __shared__ float red[768];                    // br*384 + mt*192 + c
    int rb = br * 384 + mt * 192 + c;
    red[rb] = a0; red[rb + 1] = a1; red[rb + 2] = a2; red[rb + 3] = a3;
    __syncthreads();
    if (t < 128) {
        #pragma unroll
        for (int q = 0; q < 2; ++q) {
            int o = t + q * 128;                  // 0..255
            int obr = o >> 7, omt = (o >> 6) & 1, dd = o & 63;
            int base = obr * 384 + omt * 192;
            float tot = red[base + dd] + red[base + 64 + dd] + red[base + 128 + dd];
            const float* bias = omt ? blv : bmu;
            float v = tot * (1.f / 3.f) + bias[obr * 64 + dd];
            mt_gat[((size_t)(obr * 2 + omt) * NN + d) * 64 + dd] = v;
        }
    }
}

// ---------------- finalize: bias, z, 4-way max, outputs + split-fp16 z2 -------------
__global__ void k_finalize(const float* __restrict__ muv_gcn, const float* __restrict__ gcn_bmu,
                           const float* __restrict__ gcn_blv, const float* __restrict__ mt_gat,
                           const float* __restrict__ eps_gcn, const float* __restrict__ eps_gat,
                           float* __restrict__ mu_o, float* __restrict__ lv_o,
                           unsigned short* __restrict__ z2) {
    int i = blockIdx.x * 256 + threadIdx.x;       // NN*64
    int d = i >> 6, c = i & 63;
    const size_t NN64 = (size_t)NN * 64;
    float mu, lv, zm;
    {
        float m = muv_gcn[(size_t)d * 128 + c] + gcn_bmu[c];
        float l = muv_gcn[(size_t)d * 128 + 64 + c] + gcn_blv[c];
        float z = m + eps_gcn[i] * __expf(l);
        mu = m; lv = l; zm = z;
    }
    {
        float m = muv_gcn[NN64 * 2 + (size_t)d * 128 + c] + gcn_bmu[64 + c];
        float l = muv_gcn[NN64 * 2 + (size_t)d * 128 + 64 + c] + gcn_blv[64 + c];
        float z = m + eps_gcn[NN64 + i] * __expf(l);
        mu = fmaxf(mu, m); lv = fmaxf(lv, l); zm = fmaxf(zm, z);
    }
    #pragma unroll
    for (int br = 0; br < 2; ++br) {
        float m = mt_gat[(size_t)(br * 2 + 0) * NN64 + i];
        float l = mt_gat[(size_t)(br * 2 + 1) * NN64 + i];
        float z = m + eps_gat[(size_t)br * NN64 + i] * __expf(l);
        mu = fmaxf(mu, m); lv = fmaxf(lv, l); zm = fmaxf(zm, z);
    }
    mu_o[i] = mu;
    lv_o[i] = lv;
    unsigned short hh, ll;
    splith(zm, hh, ll);
    z2[(size_t)d * 128 + c] = hh;
    z2[(size_t)d * 128 + 64 + c] = ll;
}

extern "C" void kernel_launch(void* const* d_in, const int* in_sizes, int n_in,
                              void* d_out, int out_size, void* d_ws, size_t ws_size,
                              hipStream_t stream) {
    const float* x  = (const float*)d_in[0];
    const int*   ei = (const int*)d_in[1];
    const int E = in_sizes[1] / 2;
    const int E3 = E * 3;
    const int* src = ei;
    const int* dst = ei + E;

    const float* gcn_W1  = (const float*)d_in[2];
    const float* gcn_b1  = (const float*)d_in[3];
    const float* gcn_Wmu = (const float*)d_in[4];
    const float* gcn_bmu = (const float*)d_in[5];
    const float* gcn_Wlv = (const float*)d_in[6];
    const float* gcn_blv = (const float*)d_in[7];
    const float* gat_W1  = (const float*)d_in[8];
    const float* gat_as1 = (const float*)d_in[9];
    const float* gat_ad1 = (const float*)d_in[10];
    const float* gat_b1  = (const float*)d_in[11];
    const float* gat_Wmu = (const float*)d_in[12];
    const float* gat_asmu= (const float*)d_in[13];
    const float* gat_admu= (const float*)d_in[14];
    const float* gat_bmu = (const float*)d_in[15];
    const float* gat_Wlv = (const float*)d_in[16];
    const float* gat_aslv= (const float*)d_in[17];
    const float* gat_adlv= (const float*)d_in[18];
    const float* gat_blv = (const float*)d_in[19];
    const float* eps_gcn = (const float*)d_in[20];
    const float* eps_gat = (const float*)d_in[21];

    // ---- workspace carve ----
    char* p = (char*)d_ws;
    auto alloc = [&](size_t bytes) {
        void* r = (void*)p;
        p += (bytes + 255) & ~(size_t)255;
        return r;
    };
    int*   cnt     = (int*)alloc((size_t)NN * 4);
    int*   cursor  = (int*)alloc((size_t)NN * 4);
    int*   row_ptr = (int*)alloc((size_t)(NN + 1) * 4);
    int*   csr_src = (int*)alloc((size_t)E * 4);
    float* dinv    = (float*)alloc((size_t)NN * 4);
    float* as_n1   = (float*)alloc((size_t)2 * NN * 3 * 4);
    float* ad_n1   = (float*)alloc((size_t)2 * NN * 3 * 4);
    float* wself1  = (float*)alloc((size_t)2 * NN * 3 * 4);
    float* wcsr1   = (float*)alloc((size_t)2 * E3 * 4);
    float* as_n2   = (float*)alloc((size_t)4 * NN * 3 * 4);
    float* ad_n2   = (float*)alloc((size_t)4 * NN * 3 * 4);
    float* wself2  = (float*)alloc((size_t)4 * NN * 3 * 4);
    float* wcsr2   = (float*)alloc((size_t)4 * E3 * 4);
    unsigned short* x2h      = (unsigned short*)alloc((size_t)NN * 512 * 2);
    unsigned short* wt_gcn1  = (unsigned short*)alloc((size_t)256 * 512 * 2);
    unsigned short* wt_gcnmuv= (unsigned short*)alloc((size_t)2 * 128 * 128 * 2);
    unsigned short* wt_gat1  = (unsigned short*)alloc((size_t)768 * 512 * 2);
    unsigned short* wt_gatmuv= (unsigned short*)alloc((size_t)2 * 384 * 384 * 2);
    unsigned short* xwb  = (unsigned short*)alloc((size_t)NN * 768 * 2);  // GCN uses ld 256
    unsigned short* hb   = (unsigned short*)alloc((size_t)NN * 256 * 2);
    unsigned short* hA   = (unsigned short*)alloc((size_t)NN * 256 * 2);
    float* muv_gcn = (float*)alloc((size_t)2 * NN * 128 * 4);
    unsigned short* h1s  = (unsigned short*)alloc((size_t)NN * 768 * 2);
    unsigned short* h2gb = (unsigned short*)alloc((size_t)2 * NN * 384 * 2);
    float* mt_gat  = (float*)alloc((size_t)4 * NN * 64 * 4);
    unsigned short* z2 = (unsigned short*)alloc((size_t)NN * 128 * 2);

    float* adj  = (float*)d_out;
    float* mu_o = adj + (size_t)NN * NN;
    float* lv_o = mu_o + (size_t)NN * 64;

    // ---- CSR build ----
    k_zero<<<(2 * NN + 255) / 256, 256, 0, stream>>>(cnt, 2 * NN);
    k_count<<<(E + 255) / 256, 256, 0, stream>>>(dst, cnt, E);
    k_dinv<<<(NN + 255) / 256, 256, 0, stream>>>(cnt, dinv);
    k_scan<<<1, 1024, 0, stream>>>(cnt, row_ptr);
    k_fill<<<(E + 255) / 256, 256, 0, stream>>>(src, dst, row_ptr, cursor, csr_src, E);

    // ---- precision prep (fp16) ----
    k_cvt_x<<<NN * 512 / 4 / 256, 256, 0, stream>>>(x, x2h);
    k_wT<<<dim3(16, 4, 2), 256, 0, stream>>>(gcn_W1, wt_gcn1, 512, 128, 0, 0, 128);
    k_wT<<<dim3(4, 2, 2), 256, 0, stream>>>(gcn_Wmu, wt_gcnmuv, 128, 64, (size_t)128 * 128, 0, 0);
    k_wT<<<dim3(4, 2, 2), 256, 0, stream>>>(gcn_Wlv, wt_gcnmuv, 128, 64, (size_t)128 * 128, 64, 0);
    k_wT<<<dim3(16, 12, 2), 256, 0, stream>>>(gat_W1, wt_gat1, 512, 384, 0, 0, 384);
    k_wT<<<dim3(12, 6, 2), 256, 0, stream>>>(gat_Wmu, wt_gatmuv, 384, 192, (size_t)384 * 384, 0, 0);
    k_wT<<<dim3(12, 6, 2), 256, 0, stream>>>(gat_Wlv, wt_gatmuv, 384, 192, (size_t)384 * 384, 192, 0);

    // ---- GCN (both branches batched) ----
    // g1: xwb[:, :256] = fp16(x2h @ wt_gcn1)  (K=512, N=256), ldc=256
    k_gemm2<1, 2><<<dim3(64, 4, 1), 256, 0, stream>>>(x2h, 0, 512, wt_gcn1, 0, 512,
                                                      xwb, 0, 256, 512);
    k_gcn_a1<<<NN, 64, 0, stream>>>((const uint2*)xwb, dinv, row_ptr, csr_src, gcn_b1,
                                    (uint2*)hb);
    k_gcn_a2<<<NN, 64, 0, stream>>>((const uint2*)hb, dinv, row_ptr, csr_src, (uint2*)hA);
    // g2: muv[z] = hA[z] @ wt_gcnmuv[z]  (K=128, N=128), fp32 out
    k_gemm2<1, 0><<<dim3(64, 2, 2), 256, 0, stream>>>(hA, 128, 256, wt_gcnmuv,
                                                      (size_t)128 * 128, 128,
                                                      muv_gcn, (size_t)NN * 128, 128, 128);

    // ---- GAT (both branches batched) ----
    // G1: xwb = fp16(x2h @ wt_gat1)  (K=512, N=768)
    k_gemm2<1, 2><<<dim3(64, 12, 1), 256, 0, stream>>>(x2h, 0, 512, wt_gat1, 0, 512,
                                                       xwb, 0, 768, 512);
    k_gat_log1<<<dim3(NN, 1, 2), 192, 0, stream>>>((const unsigned int*)xwb, gat_as1,
                                                   gat_ad1, as_n1, ad_n1);
    k_gat_attn<<<dim3(NN, 1, 2), 192, 0, stream>>>(as_n1, ad_n1, row_ptr, csr_src,
                                                   wcsr1, wself1, E3);
    k_gat_agg1<<<NN, 192, 0, stream>>>((const uint2*)xwb, wcsr1, wself1, row_ptr, csr_src,
                                       gat_b1, (uint2*)h1s, E3);
    // G2: h2gb[z] = fp16(h1s[z] @ wt_gatmuv[z])  (K=384, N=384)
    k_gemm2<1, 2><<<dim3(64, 6, 2), 256, 0, stream>>>(h1s, 384, 768, wt_gatmuv,
                                                      (size_t)384 * 384, 384,
                                                      h2gb, (size_t)NN * 384, 384, 384);
    k_gat_log2<<<dim3(NN, 1, 4), 192, 0, stream>>>(h2gb, gat_asmu, gat_aslv, gat_admu,
                                                   gat_adlv, as_n2, ad_n2);
    k_gat_attn<<<dim3(NN, 1, 4), 192, 0, stream>>>(as_n2, ad_n2, row_ptr, csr_src,
                                                   wcsr2, wself2, E3);
    k_gat_agg2<<<NN, 192, 0, stream>>>((const uint2*)h2gb, wcsr2, wself2, row_ptr, csr_src,
                                       gat_bmu, gat_blv, mt_gat, E3);

    // ---- finalize + adjacency (fp16 hi/lo 3-term for accuracy) ----
    k_finalize<<<NN * 64 / 256, 256, 0, stream>>>(muv_gcn, gcn_bmu, gcn_blv, mt_gat,
                                                  eps_gcn, eps_gat, mu_o, lv_o, z2);
    k_gemm2<3, 1><<<dim3(64, 128, 1), 256, 0, stream>>>(z2, 0, 128, z2, 0, 128,
                                                        adj, 0, NN, 64);
}